// Round 19
// baseline (247.818 us; speedup 1.0000x reference)
//
#include <hip/hip_runtime.h>

typedef _Float16 f16;
typedef _Float16 f16x8 __attribute__((ext_vector_type(8)));
typedef _Float16 f16x4 __attribute__((ext_vector_type(4)));
typedef float    f32x4 __attribute__((ext_vector_type(4)));
typedef float    f32x16 __attribute__((ext_vector_type(16)));
typedef unsigned u32;
typedef unsigned u32x4 __attribute__((ext_vector_type(4)));

#define GAS __attribute__((address_space(1)))
#define LAS __attribute__((address_space(3)))

template <int N> struct IC { static constexpr int v = N; };

static __device__ __forceinline__ void gload_lds16(const void* g, void* l) {
    __builtin_amdgcn_global_load_lds((const GAS void*)g, (LAS void*)l, 16, 0, 0);
}

// ---------------- weight convert + transpose: fp32 [K,N] -> f16 [N,K] ----------------
__global__ void wconv_t(const float* __restrict__ w, f16* __restrict__ wt, int K, int N) {
    __shared__ f16 t[32][33];
    const int tx = threadIdx.x, ty = threadIdx.y;
    const int n0 = blockIdx.x * 32, k0 = blockIdx.y * 32;
#pragma unroll
    for (int i = 0; i < 4; i++)
        t[ty + i * 8][tx] = (f16)w[(size_t)(k0 + ty + i * 8) * N + n0 + tx];
    __syncthreads();
#pragma unroll
    for (int i = 0; i < 4; i++)
        wt[(size_t)(n0 + ty + i * 8) * K + k0 + tx] = t[tx][ty + i * 8];
}

// ---------------- LayerNorm fp32 -> f16 (D=1024, one row per block) ----------------
__global__ __launch_bounds__(256) void ln_kernel(const float* __restrict__ x,
                                                 const float* __restrict__ w,
                                                 f16* __restrict__ h) {
    const int row = blockIdx.x, tid = threadIdx.x;
    const float4 v = reinterpret_cast<const float4*>(x)[(size_t)row * 256 + tid];
    float s = v.x + v.y + v.z + v.w;
    float q = v.x * v.x + v.y * v.y + v.z * v.z + v.w * v.w;
#pragma unroll
    for (int m = 1; m < 64; m <<= 1) { s += __shfl_xor(s, m); q += __shfl_xor(q, m); }
    __shared__ float ss[4], qq[4];
    if ((tid & 63) == 0) { ss[tid >> 6] = s; qq[tid >> 6] = q; }
    __syncthreads();
    s = ss[0] + ss[1] + ss[2] + ss[3];
    q = qq[0] + qq[1] + qq[2] + qq[3];
    const float mu = s * (1.0f / 1024.0f);
    const float var = q * (1.0f / 1024.0f) - mu * mu;
    const float rs = rsqrtf(var + 1e-5f);
    const float4 wv = reinterpret_cast<const float4*>(w)[tid];
    f16x4 o;
    o[0] = (f16)((v.x - mu) * rs * wv.x);
    o[1] = (f16)((v.y - mu) * rs * wv.y);
    o[2] = (f16)((v.z - mu) * rs * wv.z);
    o[3] = (f16)((v.w - mu) * rs * wv.w);
    reinterpret_cast<f16x4*>(h)[(size_t)row * 256 + tid] = o;
}

// ---------------- V transpose: f16 [4096,1024] -> Vt f16 [32*64, 2048] ----------------
__global__ __launch_bounds__(256) void vtrans(const f16* __restrict__ V, f16* __restrict__ Vt) {
    __shared__ f16 tl[64][72];
    const int tid = threadIdx.x;
    const int t0 = blockIdx.x * 64, bh = blockIdx.y;
    const int b = bh >> 4, hh = bh & 15;
    const int rr = tid >> 3, cc = (tid & 7) * 8;
#pragma unroll
    for (int p = 0; p < 2; p++) {
        f16x8 v = *(const f16x8*)(V + (size_t)(b * 2048 + t0 + p * 32 + rr) * 1024 + hh * 64 + cc);
#pragma unroll
        for (int j = 0; j < 8; j++) tl[p * 32 + rr][cc + j] = v[j];
    }
    __syncthreads();
#pragma unroll
    for (int p = 0; p < 2; p++) {
        const int d = p * 32 + rr;
        f16x8 o;
#pragma unroll
        for (int j = 0; j < 8; j++) o[j] = tl[cc + j][d];
        *(f16x8*)(Vt + (size_t)(bh * 64 + d) * 2048 + t0 + cc) = o;
    }
}

// ============ GEMM epilogue (shared) ============
template <int EPI>
static __device__ __forceinline__ void gemm_epi(
    int gr, int gc, float v, int N, int gx,
    const float* bias, const float* res, void* outp,
    f16* oq, f16* ok, f16* ov, int bz, int BM) {
    if (EPI == 0) {
        if (gc < 1024)      oq[(size_t)gr * 1024 + gc]        = (f16)(v * 0.70710678118654752f);
        else if (gc < 2048) ok[(size_t)gr * 1024 + gc - 1024] = (f16)v;
        else                ov[(size_t)gr * 1024 + gc - 2048] = (f16)v;
    } else if (EPI == 1) {
        ((float*)outp)[(size_t)gr * N + gc] = v + res[(size_t)gr * N + gc];
    } else if (EPI == 2) {
        const float z = 0.7978845608028654f * (v + 0.044715f * v * v * v);
        const float t = 1.0f - 2.0f / (__builtin_amdgcn_exp2f(2.8853900817779268f * z) + 1.0f);
        ((f16*)outp)[(size_t)gr * N + gc] = (f16)(0.5f * v * (1.0f + t));
    } else {
        float* P = (float*)outp + (size_t)bz * ((size_t)gx * BM) * N;
        P[(size_t)gr * N + gc] = v;
    }
}

// ---------------- 256x256 8-phase GEMM, BK=64, 8 waves (2Mx4N) ----------------
// Fine interleave, registers read one phase ahead. STAGE SCHEDULE SHIFTED (R18 fix):
// no region is staged in/before a phase where it is still read.
//   ph0: stage A1(KT+1) [opposite parity]   (A1 of KT-1 last read prev ITER ph2)
//   ph1: stage B0(KT+2) [same parity]       (B0 last read ph0)
//   ph2: stage B1(KT+2)                     (B1 last read ph0)
//   ph3: stage A0(KT+2)                     (A0 last read ph1)
// Every boundary: vmcnt(6) + lgkmcnt(0) BEFORE barrier (pre-issued ds_reads complete
// before any wave can cross and issue overwriting stages). Quarter staged exactly 4
// phases before first use; vmcnt(6) retires the 2 ops from 4 phases ago. nt even >= 4.
template <int EPI>
__global__ __launch_bounds__(512, 2) void gemm256(
    const f16* __restrict__ A, int lda,
    const f16* __restrict__ Bt, int ldb,
    const float* __restrict__ bias,
    const float* __restrict__ res,
    void* __restrict__ outp,
    f16* __restrict__ oq, f16* __restrict__ ok, f16* __restrict__ ov,
    int N, int K) {
    __shared__ alignas(16) f16 pool[8 * 8192];   // 2 parities x 4 regions x 16KB = 128KB
    const int tid = threadIdx.x;
    const int lane = tid & 63, wv = tid >> 6;
    const int wr = wv >> 2, wc = wv & 3;          // 2M x 4N waves, wave-tile 128x64
    const int m0 = blockIdx.x * 256, n0 = blockIdx.y * 256;
    const int l15 = lane & 15, lg = lane >> 4;
    const int swz = l15 & 7;                      // 8-way read-side row swizzle (0 conflicts, R15)

    f32x4 acc[8][4] = {};
    f16x8 bf[4][2], bfN[2][2], afE[2][2], afO[2][2];

    // --- staging: thread t -> chunk row t>>3, LDS slot t&7, global col16 (t&7)^((t>>3)&7) ---
    const int gcol16 = (tid & 7) ^ ((tid >> 3) & 7);
    const f16* aSrc[2][2];
    const f16* bSrc[2][2];
#pragma unroll
    for (int c = 0; c < 2; c++) {
        const int lr = c * 64 + (tid >> 3);
#pragma unroll
        for (int h = 0; h < 2; h++) {
            const int ar = ((lr >> 5) << 6) + h * 32 + (lr & 31);
            aSrc[c][h] = A + (size_t)(m0 + ar) * lda + gcol16 * 8;
            const int br = ((lr >> 6) << 7) + h * 64 + (lr & 63);
            bSrc[c][h] = Bt + (size_t)(n0 + br) * ldb + gcol16 * 8;
        }
    }
    f16* ldst = pool + tid * 8;

    auto stageQ = [&](int par, int qid, int kt) {  // qid: 0=B0 1=B1 2=A0 3=A1
        f16* d = ldst + (par * 4 + qid) * 8192;
        if (qid >= 2) {
            gload_lds16(aSrc[0][qid - 2] + kt * 64, d);
            gload_lds16(aSrc[1][qid - 2] + kt * 64, d + 4096);
        } else {
            gload_lds16(bSrc[0][qid] + kt * 64, d);
            gload_lds16(bSrc[1][qid] + kt * 64, d + 4096);
        }
    };

    // B rows: region wc&1, row (wc>>1)*64 + ni*16 + l15; slot (kk*4+lg)^swz
    auto rdBF01 = [&](int par, f16x8 (*dst)[2]) {   // writes dst[0..1][0..1]
        const f16* bb = pool + par * 32768 + (wc & 1) * 8192 + (wc >> 1) * 4096 + l15 * 64;
#pragma unroll
        for (int ni = 0; ni < 2; ni++)
#pragma unroll
            for (int kk = 0; kk < 2; kk++)
                dst[ni][kk] = *(const f16x8*)(bb + ni * 1024 + (((kk * 4 + lg) ^ swz) * 8));
    };
    auto rdBF23 = [&](int par) {
        const f16* bb = pool + par * 32768 + (wc & 1) * 8192 + (wc >> 1) * 4096 + l15 * 64;
#pragma unroll
        for (int ni = 2; ni < 4; ni++)
#pragma unroll
            for (int kk = 0; kk < 2; kk++)
                bf[ni][kk] = *(const f16x8*)(bb + ni * 1024 + (((kk * 4 + lg) ^ swz) * 8));
    };
    // A quadrant Q: region 2+(Q&1), row wr*64 + (Q>>1)*32 + mi2*16 + l15
    auto rdAF = [&](auto qc, int par, f16x8 (&af)[2][2]) {
        constexpr int Q = decltype(qc)::v;
        const f16* ab = pool + par * 32768 + (2 + (Q & 1)) * 8192
                        + wr * 4096 + (Q >> 1) * 2048 + l15 * 64;
#pragma unroll
        for (int mi2 = 0; mi2 < 2; mi2++)
#pragma unroll
            for (int kk = 0; kk < 2; kk++)
                af[mi2][kk] = *(const f16x8*)(ab + mi2 * 1024 + (((kk * 4 + lg) ^ swz) * 8));
    };
    auto doMFMA = [&](auto qc, const f16x8 (&af)[2][2]) {
        constexpr int Q = decltype(qc)::v;
        __builtin_amdgcn_s_setprio(1);
#pragma unroll
        for (int mi2 = 0; mi2 < 2; mi2++)
#pragma unroll
            for (int ni = 0; ni < 4; ni++)
#pragma unroll
                for (int kk = 0; kk < 2; kk++)
                    acc[Q * 2 + mi2][ni] = __builtin_amdgcn_mfma_f32_16x16x32_f16(
                        af[mi2][kk], bf[ni][kk], acc[Q * 2 + mi2][ni], 0, 0, 0);
        __builtin_amdgcn_s_setprio(0);
    };

#define VMW6 { asm volatile("s_waitcnt vmcnt(6) lgkmcnt(0)" ::: "memory"); __builtin_amdgcn_s_barrier(); }
#define VMW4 { asm volatile("s_waitcnt vmcnt(4) lgkmcnt(0)" ::: "memory"); __builtin_amdgcn_s_barrier(); }
#define VMW2 { asm volatile("s_waitcnt vmcnt(2) lgkmcnt(0)" ::: "memory"); __builtin_amdgcn_s_barrier(); }
#define VMW0 { asm volatile("s_waitcnt vmcnt(0) lgkmcnt(0)" ::: "memory"); __builtin_amdgcn_s_barrier(); }

#define ITER(PARV, KT, STGA1, STGN, NXT, VW0, VW1, VW2, VW3)                   \
    {                                                                          \
        rdBF23(PARV); rdAF(IC<1>{}, PARV, afO);                                \
        if (STGA1) stageQ((PARV) ^ 1, 3, (KT) + 1);                            \
        VW0; doMFMA(IC<0>{}, afE);                                             \
        rdAF(IC<2>{}, PARV, afE);                                              \
        if (STGN) stageQ(PARV, 0, (KT) + 2);                                   \
        VW1; doMFMA(IC<1>{}, afO);                                             \
        rdAF(IC<3>{}, PARV, afO);                                              \
        if (STGN) stageQ(PARV, 1, (KT) + 2);                                   \
        VW2; doMFMA(IC<2>{}, afE);                                             \
        if (NXT) { rdBF01((PARV) ^ 1, bfN); rdAF(IC<0>{}, (PARV) ^ 1, afE); }  \
        if (STGN) stageQ(PARV, 2, (KT) + 2);                                   \
        VW3; doMFMA(IC<3>{}, afO);                                             \
        if (NXT) {                                                             \
            bf[0][0] = bfN[0][0]; bf[0][1] = bfN[0][1];                        \
            bf[1][0] = bfN[1][0]; bf[1][1] = bfN[1][1];                        \
        }                                                                      \
    }

    const int nt = K >> 6;   // K-tiles of 64 (nt=16 here: even, >=4)
    // prologue: tile 0 fully + B0,B1,A0 of tile 1 (A1(tile1) staged at ITER0 ph0)
    stageQ(0, 0, 0); stageQ(0, 1, 0); stageQ(0, 2, 0); stageQ(0, 3, 0);
    stageQ(1, 0, 1); stageQ(1, 1, 1); stageQ(1, 2, 1);
    VMW6;   // tile 0's 8 ops retired; tile 1's B0,B1,A0 (6 ops) in flight
    rdBF01(0, bf);
    rdAF(IC<0>{}, 0, afE);

    for (int kt = 0; kt < nt - 2; ++kt) {
        const int par = kt & 1;
        ITER(par, kt, 1, 1, 1, VMW6, VMW6, VMW6, VMW6);
    }
    ITER((nt - 2) & 1, nt - 2, 1, 0, 1, VMW6, VMW4, VMW2, VMW0);
    ITER((nt - 1) & 1, nt - 1, 0, 0, 0, VMW0, VMW0, VMW0, VMW0);

#undef ITER
#undef VMW6
#undef VMW4
#undef VMW2
#undef VMW0

#pragma unroll
    for (int mi = 0; mi < 8; mi++)
#pragma unroll
        for (int ni = 0; ni < 4; ni++) {
            const int gc = n0 + wc * 64 + ni * 16 + l15;
            const float bb = (EPI == 3) ? 0.0f : bias[gc];
#pragma unroll
            for (int r = 0; r < 4; r++) {
                const int gr = m0 + wr * 128 + mi * 16 + lg * 4 + r;
                gemm_epi<EPI>(gr, gc, acc[mi][ni][r] + bb, N, gridDim.x,
                              bias, res, outp, oq, ok, ov, blockIdx.z, 256);
            }
        }
}

// ---------------- 128x128 GEMM, 8 waves (2Mx4N), wave-tile 64x32, vmcnt(2) (R10-proven) ----------------
template <int EPI>
__global__ __launch_bounds__(512) void gemm128(
    const f16* __restrict__ A, int lda,
    const f16* __restrict__ Bt, int ldb,
    const float* __restrict__ bias,
    const float* __restrict__ res,
    void* __restrict__ outp,
    f16* __restrict__ oq, f16* __restrict__ ok, f16* __restrict__ ov,
    int N, int K) {
    __shared__ alignas(16) f16 As[3][128 * 32];
    __shared__ alignas(16) f16 Bs[3][128 * 32];
    const int tid = threadIdx.x;
    const int lane = tid & 63, wv = tid >> 6;
    const int wr = wv >> 2, wc = wv & 3;
    const int m0 = blockIdx.x * 128, n0 = blockIdx.y * 128;
    const int l15 = lane & 15, lg = lane >> 4;

    f32x4 acc[4][2] = {};

    const int ar = tid >> 2;
    const int ac = (tid & 3) * 8;
    const size_t koff = (size_t)blockIdx.z * K;
    const f16* gA = A + (size_t)(m0 + ar) * lda + ac + koff;
    const f16* gB = Bt + (size_t)(n0 + ar) * ldb + ac + koff;
    char* lA0 = (char*)As + wv * 1024;
    char* lB0 = (char*)Bs + wv * 1024;

    auto stage = [&](int buf, int k0) {
        gload_lds16(gA + k0, lA0 + buf * 8192);
        gload_lds16(gB + k0, lB0 + buf * 8192);
    };
    auto compute = [&](int buf) {
        f16x8 af[4], bf[2];
#pragma unroll
        for (int i = 0; i < 4; i++)
            af[i] = *(const f16x8*)&As[buf][(wr * 64 + i * 16 + l15) * 32 + lg * 8];
#pragma unroll
        for (int n = 0; n < 2; n++)
            bf[n] = *(const f16x8*)&Bs[buf][(wc * 32 + n * 16 + l15) * 32 + lg * 8];
#pragma unroll
        for (int mi = 0; mi < 4; mi++)
#pragma unroll
            for (int ni = 0; ni < 2; ni++)
                acc[mi][ni] = __builtin_amdgcn_mfma_f32_16x16x32_f16(af[mi], bf[ni], acc[mi][ni], 0, 0, 0);
    };

    const int nk = K >> 5;
    stage(0, 0);
    if (nk > 1) {
        stage(1, 32);
        asm volatile("s_waitcnt vmcnt(2)" ::: "memory");
    } else {
        asm volatile("s_waitcnt vmcnt(0)" ::: "memory");
    }
    __builtin_amdgcn_s_barrier();

    for (int t = 0; t < nk; ++t) {
        const bool pref = (t + 2 < nk);
        if (pref) stage((t + 2) % 3, (t + 2) * 32);
        compute(t % 3);
        if (t + 1 < nk) {
            if (pref) asm volatile("s_waitcnt vmcnt(2)" ::: "memory");
            else      asm volatile("s_waitcnt vmcnt(0)" ::: "memory");
            __builtin_amdgcn_s_barrier();
        }
    }

#pragma unroll
    for (int mi = 0; mi < 4; mi++)
#pragma unroll
        for (int ni = 0; ni < 2; ni++) {
            const int gc = n0 + wc * 32 + ni * 16 + l15;
            const float bb = (EPI == 3) ? 0.0f : bias[gc];
#pragma unroll
            for (int r = 0; r < 4; r++) {
                const int gr = m0 + wr * 64 + mi * 16 + lg * 4 + r;
                gemm_epi<EPI>(gr, gc, acc[mi][ni][r] + bb, N, gridDim.x,
                              bias, res, outp, oq, ok, ov, blockIdx.z, 128);
            }
        }
}

// ---------------- split-K reduce: out = p0 + p1 + bias + res  (N = 1024 fp32) ----------------
__global__ __launch_bounds__(256) void kred(const float* __restrict__ p0,
                                            const float* __restrict__ p1,
                                            const float* __restrict__ bias,
                                            const float* __restrict__ res,
                                            float* __restrict__ out) {
    const size_t i = (size_t)blockIdx.x * 256 + threadIdx.x;
    const float4 a = ((const float4*)p0)[i];
    const float4 b = ((const float4*)p1)[i];
    const float4 r = ((const float4*)res)[i];
    const float4 w = ((const float4*)bias)[i & 255];
    float4 o;
    o.x = a.x + b.x + r.x + w.x;
    o.y = a.y + b.y + r.y + w.y;
    o.z = a.z + b.z + r.z + w.z;
    o.w = a.w + b.w + r.w + w.w;
    ((float4*)out)[i] = o;
}

// ---------------- causal flash attention: 8 waves, 8 interleaved qtiles, KVBLK=64 ----------------
__global__ __launch_bounds__(512) void attn_kernel(
    const f16* __restrict__ Q, const f16* __restrict__ Kb,
    const f16* __restrict__ Vt, f16* __restrict__ O) {
    __shared__ alignas(16) char pool[32768];
    const int tid = threadIdx.x, lane = tid & 63, w = tid >> 6;
    const int l31 = lane & 31, hi = lane >> 5;
    const int bx = blockIdx.x;
    const int qs = bx >> 5, bh = bx & 31;
    const int b = bh >> 4, hh = bh & 15;
    const int qtile = w * 8 + qs;
    const int q0 = qtile * 32;
    const int last = qtile >> 1;
    const int nk = ((56 + qs) >> 1) + 1;

    const f16* qrow = Q + (size_t)(b * 2048 + q0 + l31) * 1024 + hh * 64 + hi * 8;
    f16x8 qf[4];
#pragma unroll
    for (int s = 0; s < 4; s++) qf[s] = *(const f16x8*)(qrow + s * 16);

    f32x16 oacc[2] = {};
    float m = -3e38f, l = 0.0f;

    const int srow = tid >> 3, sslot = (tid & 7) ^ ((tid >> 3) & 7);
    const f16* kg = Kb + ((size_t)b * 2048 + srow) * 1024 + hh * 64 + sslot * 8;
    const f16* vg = Vt + ((size_t)bh * 64 + srow) * 2048 + sslot * 8;
    char* kld = pool + tid * 16;
    char* vld = pool + 8192 + tid * 16;

    auto stage = [&](int buf, int kt) {
        gload_lds16(kg + (size_t)kt * 65536, kld + buf * 16384);
        gload_lds16(vg + kt * 64, vld + buf * 16384);
    };

    const int rs = l31 & 7;

    auto tilestep = [&](int buf, bool diag) {
        const f16* Kbuf = (const f16*)(pool + buf * 16384);
        const f16* Vbuf = (const f16*)(pool + buf * 16384 + 8192);
        const bool doH1 = !diag || (qtile & 1);
        const int triH = qtile & 1;

        f16x8 k0[4], k1[4];
#pragma unroll
        for (int s = 0; s < 4; s++)
            k0[s] = *(const f16x8*)&Kbuf[l31 * 64 + (((s * 2 + hi) ^ rs) * 8)];
        if (doH1)
#pragma unroll
            for (int s = 0; s < 4; s++)
                k1[s] = *(const f16x8*)&Kbuf[(32 + l31) * 64 + (((s * 2 + hi) ^ rs) * 8)];

        f32x16 sacc0 = {}, sacc1 = {};
        __builtin_amdgcn_s_setprio(1);
#pragma unroll
        for (int s = 0; s < 4; s++)
            sacc0 = __builtin_amdgcn_mfma_f32_32x32x16_f16(k0[s], qf[s], sacc0, 0, 0, 0);
        if (doH1)
#pragma unroll
            for (int s = 0; s < 4; s++)
                sacc1 = __builtin_amdgcn_mfma_f32_32x32x16_f16(k1[s], qf[s], sacc1, 0, 0, 0);
        __builtin_amdgcn_s_setprio(0);

        if (diag) {
            if (triH == 0) {
#pragma unroll
                for (int r = 0; r < 16; r++) {
                    const int keyoff = (r & 3) + 8 * (r >> 2) + 4 * hi;
                    sacc0[r] = (keyoff > l31) ? -3e38f : sacc0[r];
                }
            } else {
#pragma unroll
                for (int r = 0; r < 16; r++) {
                    const int keyoff = (r & 3) + 8 * (r >> 2) + 4 * hi;
                    sacc1[r] = (keyoff > l31) ? -3e38f : sacc1[r];
                }
            }
        }
        float t8[8];
#pragma unroll
        for (int i = 0; i < 8; i++) t8[i] = fmaxf(sacc0[2 * i], sacc0[2 * i + 1]);
        if (doH1)
#pragma unroll
            for (int i = 0; i < 8; i++) t8[i] = fmaxf(t8[i], fmaxf(sacc1[2 * i], sacc1[2 * i + 1]));
#pragma unroll
        for (int i = 0; i < 4; i++) t8[i] = fmaxf(t8[i], t8[i + 4]);
        float tm = fmaxf(fmaxf(t8[0], t8[1]), fmaxf(t8[2], t8[3]));
        tm = fmaxf(tm, __shfl_xor(tm, 32));
        const bool up = tm > m + 8.0f;
        if (__any(up)) {
            const float mnew = up ? tm : m;
            const float alpha = __expf(m - mnew);
            m = mnew;
            l *= alpha;
#pragma unroll
            for (int r = 0; r < 16; r++) { oacc[0][r] *= alpha; oacc[1][r] *= alpha; }
        }
        const float mref = m * 1.44269504f;

        float psum = 0.0f;
        u32 wd[8];
        {
            float p[16];
#pragma unroll
            for (int r = 0; r < 16; r++)
                p[r] = __builtin_amdgcn_exp2f(sacc0[r] * 1.44269504f - mref);
            float s8[8];
#pragma unroll
            for (int i = 0; i < 8; i++) s8[i] = p[2 * i] + p[2 * i + 1];
#pragma unroll
            for (int i = 0; i < 4; i++) s8[i] = s8[i] + s8[i + 4];
            psum += (s8[0] + s8[1]) + (s8[2] + s8[3]);
#pragma unroll
            for (int i = 0; i < 8; i++)
                wd[i] = __builtin_bit_cast(u32, __builtin_amdgcn_cvt_pkrtz(p[2 * i], p[2 * i + 1]));
        }
        const u32 e0 = __shfl_xor(hi ? wd[0] : wd[2], 32);
        const u32 e1 = __shfl_xor(hi ? wd[1] : wd[3], 32);
        const u32 e2 = __shfl_xor(hi ? wd[4] : wd[6], 32);
        const u32 e3 = __shfl_xor(hi ? wd[5] : wd[7], 32);
        u32x4 c0, c1;
        c0[0] = hi ? e0 : wd[0]; c0[1] = hi ? e1 : wd[1];
        c0[2] = hi ? wd[2] : e0; c0[3] = hi ? wd[3] : e1;
        c1[0] = hi ? e2 : wd[4]; c1[1] = hi ? e3 : wd[5];
        c1[2] = hi ? wd[6] : e2; c1[3] = hi ? wd[7] : e3;
        const f16x8 pb00 = __builtin_bit_cast(f16x8, c0);
        const f16x8 pb01 = __builtin_bit_cast(f16x8, c1);

        f16x8 vfa, vfb;
        __builtin_amdgcn_s_setprio(1);
        vfa = *(const f16x8*)&Vbuf[l31 * 64 + ((hi ^ rs) * 8)];
        vfb = *(const f16x8*)&Vbuf[l31 * 64 + (((2 + hi) ^ rs) * 8)];
        oacc[0] = __builtin_amdgcn_mfma_f32_32x32x16_f16(vfa, pb00, oacc[0], 0, 0, 0);
        oacc[0] = __builtin_amdgcn_mfma_f32_32x32x16_f16(vfb, pb01, oacc[0], 0, 0, 0);
        vfa = *(const f16x8*)&Vbuf[(32 + l31) * 64 + ((hi ^ rs) * 8)];
        vfb = *(const f16x8*)&Vbuf[(32 + l31) * 64 + (((2 + hi) ^ rs) * 8)];
        oacc[1] = __builtin_amdgcn_mfma_f32_32x32x16_f16(vfa, pb00, oacc[1], 0, 0, 0);
        oacc[1] = __builtin_amdgcn_mfma_f32_32x32x16_f16(vfb, pb01, oacc[1], 0, 0, 0);
        __builtin_amdgcn_s_setprio(0);

        if (doH1) {
            float p[16];
#pragma unroll
            for (int r = 0; r < 16; r++)
                p[r] = __builtin_amdgcn_exp2f(sacc1[r] * 1.44269504f - mref);
            float s8[8];
#pragma unroll
            for (int i = 0; i < 8; i++) s8[i] = p[2 * i] + p[2 * i + 1];
#pragma unroll
            for (int i = 0; i < 4; i++) s8[i] = s8[i] + s8[i + 4];
            psum += (s8[0] + s8[1]) + (s8[2] + s8[3]);
#pragma unroll
            for (int i = 0; i < 8; i++)
                wd[i] = __builtin_bit_cast(u32, __builtin_amdgcn_cvt_pkrtz(p[2 * i], p[2 * i + 1]));
            const u32 f0 = __shfl_xor(hi ? wd[0] : wd[2], 32);
            const u32 f1 = __shfl_xor(hi ? wd[1] : wd[3], 32);
            const u32 f2 = __shfl_xor(hi ? wd[4] : wd[6], 32);
            const u32 f3 = __shfl_xor(hi ? wd[5] : wd[7], 32);
            u32x4 d0, d1;
            d0[0] = hi ? f0 : wd[0]; d0[1] = hi ? f1 : wd[1];
            d0[2] = hi ? wd[2] : f0; d0[3] = hi ? wd[3] : f1;
            d1[0] = hi ? f2 : wd[4]; d1[1] = hi ? f3 : wd[5];
            d1[2] = hi ? wd[6] : f2; d1[3] = hi ? wd[7] : f3;
            const f16x8 pb10 = __builtin_bit_cast(f16x8, d0);
            const f16x8 pb11 = __builtin_bit_cast(f16x8, d1);

            __builtin_amdgcn_s_setprio(1);
            vfa = *(const f16x8*)&Vbuf[l31 * 64 + (((4 + hi) ^ rs) * 8)];
            vfb = *(const f16x8*)&Vbuf[l31 * 64 + (((6 + hi) ^ rs) * 8)];
            oacc[0] = __builtin_amdgcn_mfma_f32_32x32x16_f16(vfa, pb10, oacc[0], 0, 0, 0);
            oacc[0] = __builtin_amdgcn_mfma_f32_32x32x16_f16(vfb, pb11, oacc[0], 0, 0, 0);
            vfa = *(const f16x8*)&Vbuf[(32 + l31) * 64 + (((4 + hi) ^ rs) * 8)];
            vfb = *(const f16x8*)&Vbuf[(32 + l31) * 64 + (((6 + hi) ^ rs) * 8)];
            oacc[1] = __builtin_amdgcn_mfma_f32_32x32x16_f16(vfa, pb10, oacc[1], 0, 0, 0);
            oacc[1] = __builtin_amdgcn_mfma_f32_32x32x16_f16(vfb, pb11, oacc[1], 0, 0, 0);
            __builtin_amdgcn_s_setprio(0);
        }
        psum += __shfl_xor(psum, 32);
        l += psum;
    };

    stage(0, 0);
    asm volatile("s_waitcnt vmcnt(0)" ::: "memory");
    __builtin_amdgcn_s_barrier();
    int buf = 0;
    for (int t = 0; t < nk; ++t) {
        if (t + 1 < nk) stage(buf ^ 1, t + 1);
        if (t <= last) tilestep(buf, t == last);
        asm volatile("s_waitcnt vmcnt(0)" ::: "memory");
        __builtin_amdgcn_s_barrier();
        buf ^= 1;
    }

    const float inv = 1.0f / l;
    f16* ot = (f16*)pool + (w & 3) * (32 * 72);
#pragma unroll
    for (int g = 0; g < 2; g++) {
        if ((w >> 2) == g) {
#pragma unroll
            for (int dt = 0; dt < 2; dt++)
#pragma unroll
                for (int r = 0; r < 16; r++) {
                    const int d = dt * 32 + (r & 3) + 8 * (r >> 2) + 4 * hi;
                    ot[l31 * 72 + d] = (f16)(oacc[dt][r] * inv);
                }
            asm volatile("s_waitcnt lgkmcnt(0)" ::: "memory");
#pragma unroll
            for (int i = 0; i < 4; i++) {
                const int row = i * 8 + (lane >> 3), col = (lane & 7) * 8;
                const f16x8 o8 = *(const f16x8*)&ot[row * 72 + col];
                *(f16x8*)(O + (size_t)(b * 2048 + q0 + row) * 1024 + hh * 64 + col) = o8;
            }
        }
        __syncthreads();
    }
}

extern "C" void kernel_launch(void* const* d_in, const int* in_sizes, int n_in,
                              void* d_out, int out_size, void* d_ws, size_t ws_size,
                              hipStream_t stream) {
    const float* x      = (const float*)d_in[0];
    const float* ln1_w  = (const float*)d_in[1];
    const float* attn_w = (const float*)d_in[2];
    const float* attn_b = (const float*)d_in[3];
    const float* proj_w = (const float*)d_in[4];
    const float* proj_b = (const float*)d_in[5];
    const float* ln2_w  = (const float*)d_in[6];
    const float* li1_w  = (const float*)d_in[7];
    const float* li1_b  = (const float*)d_in[8];
    const float* li2_w  = (const float*)d_in[9];
    const float* li2_b  = (const float*)d_in[10];
    float* out = (float*)d_out;

    char* ws = (char*)d_ws;
    size_t off = 0;
    auto alloc = [&](size_t bytes) { void* p = ws + off; off += (bytes + 255) & ~(size_t)255; return p; };
    f16* W1t = (f16*)alloc((size_t)3072 * 1024 * 2);
    f16* W2t = (f16*)alloc((size_t)1024 * 1024 * 2);
    f16* W3t = (f16*)alloc((size_t)4096 * 1024 * 2);
    f16* W4t = (f16*)alloc((size_t)1024 * 4096 * 2);
    f16* h   = (f16*)alloc((size_t)4096 * 1024 * 2);
    f16* Qb  = (f16*)alloc((size_t)4096 * 1024 * 2);
    f16* Kb  = (f16*)alloc((size_t)4096 * 1024 * 2);
    f16* Vb  = (f16*)alloc((size_t)4096 * 1024 * 2);
    f16* Vt  = (f16*)alloc((size_t)4096 * 1024 * 2);
    f16* Ob  = (f16*)alloc((size_t)4096 * 1024 * 2);
    float* x1 = (float*)alloc((size_t)4096 * 1024 * 4);
    float* P  = (float*)alloc((size_t)2 * 4096 * 1024 * 4);  // split-K partials
    f16* Ab = Qb;  // 4096x4096 f16 aliases Qb..Vt (33.5 MB), dead after attention

    dim3 b328(32, 8);
    wconv_t<<<dim3(96, 32),  b328, 0, stream>>>(attn_w, W1t, 1024, 3072);
    wconv_t<<<dim3(32, 32),  b328, 0, stream>>>(proj_w, W2t, 1024, 1024);
    wconv_t<<<dim3(128, 32), b328, 0, stream>>>(li1_w,  W3t, 1024, 4096);
    wconv_t<<<dim3(32, 128), b328, 0, stream>>>(li2_w,  W4t, 4096, 1024);

    ln_kernel<<<4096, 256, 0, stream>>>(x, ln1_w, h);
    gemm256<0><<<dim3(16, 12), 512, 0, stream>>>(h, 1024, W1t, 1024, attn_b, nullptr,
                                                 nullptr, Qb, Kb, Vb, 3072, 1024);
    vtrans<<<dim3(32, 32), 256, 0, stream>>>(Vb, Vt);
    attn_kernel<<<256, 512, 0, stream>>>(Qb, Kb, Vt, Ob);
    gemm128<1><<<dim3(32, 8), 512, 0, stream>>>(Ob, 1024, W2t, 1024, proj_b, x,
                                                x1, nullptr, nullptr, nullptr, 1024, 1024);
    ln_kernel<<<4096, 256, 0, stream>>>(x1, ln2_w, h);
    gemm256<2><<<dim3(16, 16), 512, 0, stream>>>(h, 1024, W3t, 1024, li1_b, nullptr,
                                                 Ab, nullptr, nullptr, nullptr, 4096, 1024);
    // down-proj: split-K=2 (K=4096 -> 2x2048), 128^2 tile (512 blocks = 2/CU), fused reduce
    gemm128<3><<<dim3(32, 8, 2), 512, 0, stream>>>(Ab, 4096, W4t, 4096, nullptr, nullptr,
                                                   P, nullptr, nullptr, nullptr, 1024, 2048);
    kred<<<4096, 256, 0, stream>>>(P, P + (size_t)4096 * 1024, li2_b, x1, out);
}

// Round 20
// 246.592 us; speedup vs baseline: 1.0050x; 1.0050x over previous
//
#include <hip/hip_runtime.h>

typedef _Float16 f16;
typedef _Float16 f16x8 __attribute__((ext_vector_type(8)));
typedef _Float16 f16x4 __attribute__((ext_vector_type(4)));
typedef float    f32x4 __attribute__((ext_vector_type(4)));
typedef float    f32x16 __attribute__((ext_vector_type(16)));
typedef unsigned u32;
typedef unsigned u32x4 __attribute__((ext_vector_type(4)));

#define GAS __attribute__((address_space(1)))
#define LAS __attribute__((address_space(3)))

template <int N> struct IC { static constexpr int v = N; };

static __device__ __forceinline__ void gload_lds16(const void* g, void* l) {
    __builtin_amdgcn_global_load_lds((const GAS void*)g, (LAS void*)l, 16, 0, 0);
}

// ---------------- weight convert + transpose: fp32 [K,N] -> f16 [N,K] ----------------
__global__ void wconv_t(const float* __restrict__ w, f16* __restrict__ wt, int K, int N) {
    __shared__ f16 t[32][33];
    const int tx = threadIdx.x, ty = threadIdx.y;
    const int n0 = blockIdx.x * 32, k0 = blockIdx.y * 32;
#pragma unroll
    for (int i = 0; i < 4; i++)
        t[ty + i * 8][tx] = (f16)w[(size_t)(k0 + ty + i * 8) * N + n0 + tx];
    __syncthreads();
#pragma unroll
    for (int i = 0; i < 4; i++)
        wt[(size_t)(n0 + ty + i * 8) * K + k0 + tx] = t[tx][ty + i * 8];
}

// ---------------- LayerNorm fp32 -> f16 (D=1024, one row per block) ----------------
__global__ __launch_bounds__(256) void ln_kernel(const float* __restrict__ x,
                                                 const float* __restrict__ w,
                                                 f16* __restrict__ h) {
    const int row = blockIdx.x, tid = threadIdx.x;
    const float4 v = reinterpret_cast<const float4*>(x)[(size_t)row * 256 + tid];
    float s = v.x + v.y + v.z + v.w;
    float q = v.x * v.x + v.y * v.y + v.z * v.z + v.w * v.w;
#pragma unroll
    for (int m = 1; m < 64; m <<= 1) { s += __shfl_xor(s, m); q += __shfl_xor(q, m); }
    __shared__ float ss[4], qq[4];
    if ((tid & 63) == 0) { ss[tid >> 6] = s; qq[tid >> 6] = q; }
    __syncthreads();
    s = ss[0] + ss[1] + ss[2] + ss[3];
    q = qq[0] + qq[1] + qq[2] + qq[3];
    const float mu = s * (1.0f / 1024.0f);
    const float var = q * (1.0f / 1024.0f) - mu * mu;
    const float rs = rsqrtf(var + 1e-5f);
    const float4 wv = reinterpret_cast<const float4*>(w)[tid];
    f16x4 o;
    o[0] = (f16)((v.x - mu) * rs * wv.x);
    o[1] = (f16)((v.y - mu) * rs * wv.y);
    o[2] = (f16)((v.z - mu) * rs * wv.z);
    o[3] = (f16)((v.w - mu) * rs * wv.w);
    reinterpret_cast<f16x4*>(h)[(size_t)row * 256 + tid] = o;
}

// ---------------- V transpose: f16 [4096,1024] -> Vt f16 [32*64, 2048] ----------------
__global__ __launch_bounds__(256) void vtrans(const f16* __restrict__ V, f16* __restrict__ Vt) {
    __shared__ f16 tl[64][72];
    const int tid = threadIdx.x;
    const int t0 = blockIdx.x * 64, bh = blockIdx.y;
    const int b = bh >> 4, hh = bh & 15;
    const int rr = tid >> 3, cc = (tid & 7) * 8;
#pragma unroll
    for (int p = 0; p < 2; p++) {
        f16x8 v = *(const f16x8*)(V + (size_t)(b * 2048 + t0 + p * 32 + rr) * 1024 + hh * 64 + cc);
#pragma unroll
        for (int j = 0; j < 8; j++) tl[p * 32 + rr][cc + j] = v[j];
    }
    __syncthreads();
#pragma unroll
    for (int p = 0; p < 2; p++) {
        const int d = p * 32 + rr;
        f16x8 o;
#pragma unroll
        for (int j = 0; j < 8; j++) o[j] = tl[cc + j][d];
        *(f16x8*)(Vt + (size_t)(bh * 64 + d) * 2048 + t0 + cc) = o;
    }
}

// ============ GEMM epilogue (shared) ============
template <int EPI>
static __device__ __forceinline__ void gemm_epi(
    int gr, int gc, float v, int N, int gx,
    const float* bias, const float* res, void* outp,
    f16* oq, f16* ok, f16* ov, int bz, int BM) {
    if (EPI == 0) {
        if (gc < 1024)      oq[(size_t)gr * 1024 + gc]        = (f16)(v * 0.70710678118654752f);
        else if (gc < 2048) ok[(size_t)gr * 1024 + gc - 1024] = (f16)v;
        else                ov[(size_t)gr * 1024 + gc - 2048] = (f16)v;
    } else if (EPI == 1) {
        ((float*)outp)[(size_t)gr * N + gc] = v + res[(size_t)gr * N + gc];
    } else if (EPI == 2) {
        const float z = 0.7978845608028654f * (v + 0.044715f * v * v * v);
        const float t = 1.0f - 2.0f / (__builtin_amdgcn_exp2f(2.8853900817779268f * z) + 1.0f);
        ((f16*)outp)[(size_t)gr * N + gc] = (f16)(0.5f * v * (1.0f + t));
    } else {
        float* P = (float*)outp + (size_t)bz * ((size_t)gx * BM) * N;
        P[(size_t)gr * N + gc] = v;
    }
}

// ---------------- 256x256 8-phase GEMM, BK=64, 8 waves (2Mx4N) ----------------
// Coarse 8-phase (Round-15 best-measured: total 246.3us, 0 bank conflicts).
// Quarter-tiles {B0,B1,A0,A1} of 16KB (2 gload_lds/thread); per phase: stage 1 quarter,
// vmcnt(6), barrier, ds_read quadrant, 16 MFMA. Rows are 64 f16 (128B): full 8-slot XOR
// swizzle (slot ^= row&7) both sides -- attention-proven involution, spans all 32 banks.
template <int EPI>
__global__ __launch_bounds__(512, 2) void gemm256(
    const f16* __restrict__ A, int lda,
    const f16* __restrict__ Bt, int ldb,
    const float* __restrict__ bias,
    const float* __restrict__ res,
    void* __restrict__ outp,
    f16* __restrict__ oq, f16* __restrict__ ok, f16* __restrict__ ov,
    int N, int K) {
    __shared__ alignas(16) f16 pool[8 * 8192];   // 8 quarter-regions x 16KB = 128KB
    const int tid = threadIdx.x;
    const int lane = tid & 63, wv = tid >> 6;
    const int wr = wv >> 2, wc = wv & 3;          // 2M x 4N waves, wave-tile 128x64
    const int m0 = blockIdx.x * 256, n0 = blockIdx.y * 256;
    const int l15 = lane & 15, lg = lane >> 4;
    const int swz = l15 & 7;                      // read-side row swizzle (8-way)

    f32x4 acc[8][4] = {};
    f16x8 bf[4][2];

    // --- staging: thread t -> chunk row t>>3, LDS slot t&7, global col16 (t&7)^((t>>3)&7) ---
    const int gcol16 = (tid & 7) ^ ((tid >> 3) & 7);
    const f16* aSrc[2][2];
    const f16* bSrc[2][2];
#pragma unroll
    for (int c = 0; c < 2; c++) {
        const int lr = c * 64 + (tid >> 3);       // local row 0..127
#pragma unroll
        for (int h = 0; h < 2; h++) {
            const int ar = ((lr >> 5) << 6) + h * 32 + (lr & 31);   // A global row (half h)
            aSrc[c][h] = A + (size_t)(m0 + ar) * lda + gcol16 * 8;
            const int br = ((lr >> 6) << 7) + h * 64 + (lr & 63);   // B global row (half h)
            bSrc[c][h] = Bt + (size_t)(n0 + br) * ldb + gcol16 * 8;
        }
    }
    f16* ldst = pool + tid * 8;   // linear LDS dest: + region*8192 + c*4096 (f16 units)

    auto stageQ = [&](int par, int qid, int kt) {  // qid: 0=B0 1=B1 2=A0 3=A1
        f16* d = ldst + (par * 4 + qid) * 8192;
        if (qid >= 2) {
            gload_lds16(aSrc[0][qid - 2] + kt * 64, d);
            gload_lds16(aSrc[1][qid - 2] + kt * 64, d + 4096);
        } else {
            gload_lds16(bSrc[0][qid] + kt * 64, d);
            gload_lds16(bSrc[1][qid] + kt * 64, d + 4096);
        }
    };

    auto loadB = [&](int par) {
        // region wc&1, lr = (wc>>1)*64 + ni*16 + l15; slot (kk*4+lg)^swz
        const f16* bb = pool + par * 32768 + (wc & 1) * 8192 + (wc >> 1) * 4096 + l15 * 64;
#pragma unroll
        for (int ni = 0; ni < 4; ni++)
#pragma unroll
            for (int kk = 0; kk < 2; kk++)
                bf[ni][kk] = *(const f16x8*)(bb + ni * 1024 + (((kk * 4 + lg) ^ swz) * 8));
    };
    auto computeQ = [&](int par, auto qc) {
        constexpr int Q = decltype(qc)::v;
        // region 2+(Q&1), lr = wr*64 + (Q>>1)*32 + mi2*16 + l15
        const f16* ab = pool + par * 32768 + (2 + (Q & 1)) * 8192
                        + wr * 4096 + (Q >> 1) * 2048 + l15 * 64;
        f16x8 af[2][2];
#pragma unroll
        for (int mi2 = 0; mi2 < 2; mi2++)
#pragma unroll
            for (int kk = 0; kk < 2; kk++)
                af[mi2][kk] = *(const f16x8*)(ab + mi2 * 1024 + (((kk * 4 + lg) ^ swz) * 8));
        __builtin_amdgcn_s_setprio(1);
#pragma unroll
        for (int mi2 = 0; mi2 < 2; mi2++)
#pragma unroll
            for (int ni = 0; ni < 4; ni++)
#pragma unroll
                for (int kk = 0; kk < 2; kk++)
                    acc[Q * 2 + mi2][ni] = __builtin_amdgcn_mfma_f32_16x16x32_f16(
                        af[mi2][kk], bf[ni][kk], acc[Q * 2 + mi2][ni], 0, 0, 0);
        __builtin_amdgcn_s_setprio(0);
    };

#define VMW(n) asm volatile("s_waitcnt vmcnt(" #n ")" ::: "memory"); __builtin_amdgcn_s_barrier()

    const int nt = K >> 6;   // K-tiles of 64
    // prologue: all 4 quarters of tile 0 + B0 of tile 1
    stageQ(0, 0, 0); stageQ(0, 1, 0); stageQ(0, 2, 0); stageQ(0, 3, 0);
    stageQ(1, 0, 1);
    VMW(6);

    for (int kt = 0; kt < nt - 2; ++kt) {
        const int par = kt & 1, parn = par ^ 1;
        stageQ(parn, 1, kt + 1); VMW(6); loadB(par); computeQ(par, IC<0>{});
        stageQ(parn, 2, kt + 1); VMW(6); computeQ(par, IC<1>{});
        stageQ(parn, 3, kt + 1); VMW(6); computeQ(par, IC<2>{});
        stageQ(par, 0, kt + 2);  VMW(6); computeQ(par, IC<3>{});
    }
    {   // kt = nt-2: last full-stage tile (no B0 of tile nt)
        const int kt = nt - 2, par = kt & 1, parn = par ^ 1;
        stageQ(parn, 1, kt + 1); VMW(6); loadB(par); computeQ(par, IC<0>{});
        stageQ(parn, 2, kt + 1); VMW(6); computeQ(par, IC<1>{});
        stageQ(parn, 3, kt + 1); VMW(6); computeQ(par, IC<2>{});
        VMW(4); computeQ(par, IC<3>{});
    }
    {   // kt = nt-1: drain
        const int par = (nt - 1) & 1;
        VMW(2); loadB(par); computeQ(par, IC<0>{});
        VMW(0); computeQ(par, IC<1>{});
        computeQ(par, IC<2>{});
        computeQ(par, IC<3>{});
    }
#undef VMW

#pragma unroll
    for (int mi = 0; mi < 8; mi++)
#pragma unroll
        for (int ni = 0; ni < 4; ni++) {
            const int gc = n0 + wc * 64 + ni * 16 + l15;
            const float bb = (EPI == 3) ? 0.0f : bias[gc];
#pragma unroll
            for (int r = 0; r < 4; r++) {
                const int gr = m0 + wr * 128 + mi * 16 + lg * 4 + r;
                gemm_epi<EPI>(gr, gc, acc[mi][ni][r] + bb, N, gridDim.x,
                              bias, res, outp, oq, ok, ov, blockIdx.z, 256);
            }
        }
}

// ---------------- 128x128 GEMM, 8 waves (2Mx4N), wave-tile 64x32, vmcnt(2) (R10-proven) ----------------
template <int EPI>
__global__ __launch_bounds__(512) void gemm128(
    const f16* __restrict__ A, int lda,
    const f16* __restrict__ Bt, int ldb,
    const float* __restrict__ bias,
    const float* __restrict__ res,
    void* __restrict__ outp,
    f16* __restrict__ oq, f16* __restrict__ ok, f16* __restrict__ ov,
    int N, int K) {
    __shared__ alignas(16) f16 As[3][128 * 32];
    __shared__ alignas(16) f16 Bs[3][128 * 32];
    const int tid = threadIdx.x;
    const int lane = tid & 63, wv = tid >> 6;
    const int wr = wv >> 2, wc = wv & 3;
    const int m0 = blockIdx.x * 128, n0 = blockIdx.y * 128;
    const int l15 = lane & 15, lg = lane >> 4;

    f32x4 acc[4][2] = {};

    const int ar = tid >> 2;
    const int ac = (tid & 3) * 8;
    const size_t koff = (size_t)blockIdx.z * K;
    const f16* gA = A + (size_t)(m0 + ar) * lda + ac + koff;
    const f16* gB = Bt + (size_t)(n0 + ar) * ldb + ac + koff;
    char* lA0 = (char*)As + wv * 1024;
    char* lB0 = (char*)Bs + wv * 1024;

    auto stage = [&](int buf, int k0) {
        gload_lds16(gA + k0, lA0 + buf * 8192);
        gload_lds16(gB + k0, lB0 + buf * 8192);
    };
    auto compute = [&](int buf) {
        f16x8 af[4], bf[2];
#pragma unroll
        for (int i = 0; i < 4; i++)
            af[i] = *(const f16x8*)&As[buf][(wr * 64 + i * 16 + l15) * 32 + lg * 8];
#pragma unroll
        for (int n = 0; n < 2; n++)
            bf[n] = *(const f16x8*)&Bs[buf][(wc * 32 + n * 16 + l15) * 32 + lg * 8];
#pragma unroll
        for (int mi = 0; mi < 4; mi++)
#pragma unroll
            for (int ni = 0; ni < 2; ni++)
                acc[mi][ni] = __builtin_amdgcn_mfma_f32_16x16x32_f16(af[mi], bf[ni], acc[mi][ni], 0, 0, 0);
    };

    const int nk = K >> 5;
    stage(0, 0);
    if (nk > 1) {
        stage(1, 32);
        asm volatile("s_waitcnt vmcnt(2)" ::: "memory");
    } else {
        asm volatile("s_waitcnt vmcnt(0)" ::: "memory");
    }
    __builtin_amdgcn_s_barrier();

    for (int t = 0; t < nk; ++t) {
        const bool pref = (t + 2 < nk);
        if (pref) stage((t + 2) % 3, (t + 2) * 32);
        compute(t % 3);
        if (t + 1 < nk) {
            if (pref) asm volatile("s_waitcnt vmcnt(2)" ::: "memory");
            else      asm volatile("s_waitcnt vmcnt(0)" ::: "memory");
            __builtin_amdgcn_s_barrier();
        }
    }

#pragma unroll
    for (int mi = 0; mi < 4; mi++)
#pragma unroll
        for (int ni = 0; ni < 2; ni++) {
            const int gc = n0 + wc * 32 + ni * 16 + l15;
            const float bb = (EPI == 3) ? 0.0f : bias[gc];
#pragma unroll
            for (int r = 0; r < 4; r++) {
                const int gr = m0 + wr * 64 + mi * 16 + lg * 4 + r;
                gemm_epi<EPI>(gr, gc, acc[mi][ni][r] + bb, N, gridDim.x,
                              bias, res, outp, oq, ok, ov, blockIdx.z, 128);
            }
        }
}

// ---------------- split-K reduce: out = p0 + p1 + bias + res  (N = 1024 fp32) ----------------
__global__ __launch_bounds__(256) void kred(const float* __restrict__ p0,
                                            const float* __restrict__ p1,
                                            const float* __restrict__ bias,
                                            const float* __restrict__ res,
                                            float* __restrict__ out) {
    const size_t i = (size_t)blockIdx.x * 256 + threadIdx.x;
    const float4 a = ((const float4*)p0)[i];
    const float4 b = ((const float4*)p1)[i];
    const float4 r = ((const float4*)res)[i];
    const float4 w = ((const float4*)bias)[i & 255];
    float4 o;
    o.x = a.x + b.x + r.x + w.x;
    o.y = a.y + b.y + r.y + w.y;
    o.z = a.z + b.z + r.z + w.z;
    o.w = a.w + b.w + r.w + w.w;
    ((float4*)out)[i] = o;
}

// ---------------- causal flash attention: 8 waves, 8 interleaved qtiles, KVBLK=64 ----------------
__global__ __launch_bounds__(512) void attn_kernel(
    const f16* __restrict__ Q, const f16* __restrict__ Kb,
    const f16* __restrict__ Vt, f16* __restrict__ O) {
    __shared__ alignas(16) char pool[32768];
    const int tid = threadIdx.x, lane = tid & 63, w = tid >> 6;
    const int l31 = lane & 31, hi = lane >> 5;
    const int bx = blockIdx.x;
    const int qs = bx >> 5, bh = bx & 31;
    const int b = bh >> 4, hh = bh & 15;
    const int qtile = w * 8 + qs;
    const int q0 = qtile * 32;
    const int last = qtile >> 1;
    const int nk = ((56 + qs) >> 1) + 1;

    const f16* qrow = Q + (size_t)(b * 2048 + q0 + l31) * 1024 + hh * 64 + hi * 8;
    f16x8 qf[4];
#pragma unroll
    for (int s = 0; s < 4; s++) qf[s] = *(const f16x8*)(qrow + s * 16);

    f32x16 oacc[2] = {};
    float m = -3e38f, l = 0.0f;

    const int srow = tid >> 3, sslot = (tid & 7) ^ ((tid >> 3) & 7);
    const f16* kg = Kb + ((size_t)b * 2048 + srow) * 1024 + hh * 64 + sslot * 8;
    const f16* vg = Vt + ((size_t)bh * 64 + srow) * 2048 + sslot * 8;
    char* kld = pool + tid * 16;
    char* vld = pool + 8192 + tid * 16;

    auto stage = [&](int buf, int kt) {
        gload_lds16(kg + (size_t)kt * 65536, kld + buf * 16384);
        gload_lds16(vg + kt * 64, vld + buf * 16384);
    };

    const int rs = l31 & 7;

    auto tilestep = [&](int buf, bool diag) {
        const f16* Kbuf = (const f16*)(pool + buf * 16384);
        const f16* Vbuf = (const f16*)(pool + buf * 16384 + 8192);
        const bool doH1 = !diag || (qtile & 1);
        const int triH = qtile & 1;

        f16x8 k0[4], k1[4];
#pragma unroll
        for (int s = 0; s < 4; s++)
            k0[s] = *(const f16x8*)&Kbuf[l31 * 64 + (((s * 2 + hi) ^ rs) * 8)];
        if (doH1)
#pragma unroll
            for (int s = 0; s < 4; s++)
                k1[s] = *(const f16x8*)&Kbuf[(32 + l31) * 64 + (((s * 2 + hi) ^ rs) * 8)];

        f32x16 sacc0 = {}, sacc1 = {};
        __builtin_amdgcn_s_setprio(1);
#pragma unroll
        for (int s = 0; s < 4; s++)
            sacc0 = __builtin_amdgcn_mfma_f32_32x32x16_f16(k0[s], qf[s], sacc0, 0, 0, 0);
        if (doH1)
#pragma unroll
            for (int s = 0; s < 4; s++)
                sacc1 = __builtin_amdgcn_mfma_f32_32x32x16_f16(k1[s], qf[s], sacc1, 0, 0, 0);
        __builtin_amdgcn_s_setprio(0);

        if (diag) {
            if (triH == 0) {
#pragma unroll
                for (int r = 0; r < 16; r++) {
                    const int keyoff = (r & 3) + 8 * (r >> 2) + 4 * hi;
                    sacc0[r] = (keyoff > l31) ? -3e38f : sacc0[r];
                }
            } else {
#pragma unroll
                for (int r = 0; r < 16; r++) {
                    const int keyoff = (r & 3) + 8 * (r >> 2) + 4 * hi;
                    sacc1[r] = (keyoff > l31) ? -3e38f : sacc1[r];
                }
            }
        }
        float t8[8];
#pragma unroll
        for (int i = 0; i < 8; i++) t8[i] = fmaxf(sacc0[2 * i], sacc0[2 * i + 1]);
        if (doH1)
#pragma unroll
            for (int i = 0; i < 8; i++) t8[i] = fmaxf(t8[i], fmaxf(sacc1[2 * i], sacc1[2 * i + 1]));
#pragma unroll
        for (int i = 0; i < 4; i++) t8[i] = fmaxf(t8[i], t8[i + 4]);
        float tm = fmaxf(fmaxf(t8[0], t8[1]), fmaxf(t8[2], t8[3]));
        tm = fmaxf(tm, __shfl_xor(tm, 32));
        const bool up = tm > m + 8.0f;
        if (__any(up)) {
            const float mnew = up ? tm : m;
            const float alpha = __expf(m - mnew);
            m = mnew;
            l *= alpha;
#pragma unroll
            for (int r = 0; r < 16; r++) { oacc[0][r] *= alpha; oacc[1][r] *= alpha; }
        }
        const float mref = m * 1.44269504f;

        float psum = 0.0f;
        u32 wd[8];
        {
            float p[16];
#pragma unroll
            for (int r = 0; r < 16; r++)
                p[r] = __builtin_amdgcn_exp2f(sacc0[r] * 1.44269504f - mref);
            float s8[8];
#pragma unroll
            for (int i = 0; i < 8; i++) s8[i] = p[2 * i] + p[2 * i + 1];
#pragma unroll
            for (int i = 0; i < 4; i++) s8[i] = s8[i] + s8[i + 4];
            psum += (s8[0] + s8[1]) + (s8[2] + s8[3]);
#pragma unroll
            for (int i = 0; i < 8; i++)
                wd[i] = __builtin_bit_cast(u32, __builtin_amdgcn_cvt_pkrtz(p[2 * i], p[2 * i + 1]));
        }
        const u32 e0 = __shfl_xor(hi ? wd[0] : wd[2], 32);
        const u32 e1 = __shfl_xor(hi ? wd[1] : wd[3], 32);
        const u32 e2 = __shfl_xor(hi ? wd[4] : wd[6], 32);
        const u32 e3 = __shfl_xor(hi ? wd[5] : wd[7], 32);
        u32x4 c0, c1;
        c0[0] = hi ? e0 : wd[0]; c0[1] = hi ? e1 : wd[1];
        c0[2] = hi ? wd[2] : e0; c0[3] = hi ? wd[3] : e1;
        c1[0] = hi ? e2 : wd[4]; c1[1] = hi ? e3 : wd[5];
        c1[2] = hi ? wd[6] : e2; c1[3] = hi ? wd[7] : e3;
        const f16x8 pb00 = __builtin_bit_cast(f16x8, c0);
        const f16x8 pb01 = __builtin_bit_cast(f16x8, c1);

        f16x8 vfa, vfb;
        __builtin_amdgcn_s_setprio(1);
        vfa = *(const f16x8*)&Vbuf[l31 * 64 + ((hi ^ rs) * 8)];
        vfb = *(const f16x8*)&Vbuf[l31 * 64 + (((2 + hi) ^ rs) * 8)];
        oacc[0] = __builtin_amdgcn_mfma_f32_32x32x16_f16(vfa, pb00, oacc[0], 0, 0, 0);
        oacc[0] = __builtin_amdgcn_mfma_f32_32x32x16_f16(vfb, pb01, oacc[0], 0, 0, 0);
        vfa = *(const f16x8*)&Vbuf[(32 + l31) * 64 + ((hi ^ rs) * 8)];
        vfb = *(const f16x8*)&Vbuf[(32 + l31) * 64 + (((2 + hi) ^ rs) * 8)];
        oacc[1] = __builtin_amdgcn_mfma_f32_32x32x16_f16(vfa, pb00, oacc[1], 0, 0, 0);
        oacc[1] = __builtin_amdgcn_mfma_f32_32x32x16_f16(vfb, pb01, oacc[1], 0, 0, 0);
        __builtin_amdgcn_s_setprio(0);

        if (doH1) {
            float p[16];
#pragma unroll
            for (int r = 0; r < 16; r++)
                p[r] = __builtin_amdgcn_exp2f(sacc1[r] * 1.44269504f - mref);
            float s8[8];
#pragma unroll
            for (int i = 0; i < 8; i++) s8[i] = p[2 * i] + p[2 * i + 1];
#pragma unroll
            for (int i = 0; i < 4; i++) s8[i] = s8[i] + s8[i + 4];
            psum += (s8[0] + s8[1]) + (s8[2] + s8[3]);
#pragma unroll
            for (int i = 0; i < 8; i++)
                wd[i] = __builtin_bit_cast(u32, __builtin_amdgcn_cvt_pkrtz(p[2 * i], p[2 * i + 1]));
            const u32 f0 = __shfl_xor(hi ? wd[0] : wd[2], 32);
            const u32 f1 = __shfl_xor(hi ? wd[1] : wd[3], 32);
            const u32 f2 = __shfl_xor(hi ? wd[4] : wd[6], 32);
            const u32 f3 = __shfl_xor(hi ? wd[5] : wd[7], 32);
            u32x4 d0, d1;
            d0[0] = hi ? f0 : wd[0]; d0[1] = hi ? f1 : wd[1];
            d0[2] = hi ? wd[2] : f0; d0[3] = hi ? wd[3] : f1;
            d1[0] = hi ? f2 : wd[4]; d1[1] = hi ? f3 : wd[5];
            d1[2] = hi ? wd[6] : f2; d1[3] = hi ? wd[7] : f3;
            const f16x8 pb10 = __builtin_bit_cast(f16x8, d0);
            const f16x8 pb11 = __builtin_bit_cast(f16x8, d1);

            __builtin_amdgcn_s_setprio(1);
            vfa = *(const f16x8*)&Vbuf[l31 * 64 + (((4 + hi) ^ rs) * 8)];
            vfb = *(const f16x8*)&Vbuf[l31 * 64 + (((6 + hi) ^ rs) * 8)];
            oacc[0] = __builtin_amdgcn_mfma_f32_32x32x16_f16(vfa, pb10, oacc[0], 0, 0, 0);
            oacc[0] = __builtin_amdgcn_mfma_f32_32x32x16_f16(vfb, pb11, oacc[0], 0, 0, 0);
            vfa = *(const f16x8*)&Vbuf[(32 + l31) * 64 + (((4 + hi) ^ rs) * 8)];
            vfb = *(const f16x8*)&Vbuf[(32 + l31) * 64 + (((6 + hi) ^ rs) * 8)];
            oacc[1] = __builtin_amdgcn_mfma_f32_32x32x16_f16(vfa, pb10, oacc[1], 0, 0, 0);
            oacc[1] = __builtin_amdgcn_mfma_f32_32x32x16_f16(vfb, pb11, oacc[1], 0, 0, 0);
            __builtin_amdgcn_s_setprio(0);
        }
        psum += __shfl_xor(psum, 32);
        l += psum;
    };

    stage(0, 0);
    asm volatile("s_waitcnt vmcnt(0)" ::: "memory");
    __builtin_amdgcn_s_barrier();
    int buf = 0;
    for (int t = 0; t < nk; ++t) {
        if (t + 1 < nk) stage(buf ^ 1, t + 1);
        if (t <= last) tilestep(buf, t == last);
        asm volatile("s_waitcnt vmcnt(0)" ::: "memory");
        __builtin_amdgcn_s_barrier();
        buf ^= 1;
    }

    const float inv = 1.0f / l;
    f16* ot = (f16*)pool + (w & 3) * (32 * 72);
#pragma unroll
    for (int g = 0; g < 2; g++) {
        if ((w >> 2) == g) {
#pragma unroll
            for (int dt = 0; dt < 2; dt++)
#pragma unroll
                for (int r = 0; r < 16; r++) {
                    const int d = dt * 32 + (r & 3) + 8 * (r >> 2) + 4 * hi;
                    ot[l31 * 72 + d] = (f16)(oacc[dt][r] * inv);
                }
            asm volatile("s_waitcnt lgkmcnt(0)" ::: "memory");
#pragma unroll
            for (int i = 0; i < 4; i++) {
                const int row = i * 8 + (lane >> 3), col = (lane & 7) * 8;
                const f16x8 o8 = *(const f16x8*)&ot[row * 72 + col];
                *(f16x8*)(O + (size_t)(b * 2048 + q0 + row) * 1024 + hh * 64 + col) = o8;
            }
        }
        __syncthreads();
    }
}

extern "C" void kernel_launch(void* const* d_in, const int* in_sizes, int n_in,
                              void* d_out, int out_size, void* d_ws, size_t ws_size,
                              hipStream_t stream) {
    const float* x      = (const float*)d_in[0];
    const float* ln1_w  = (const float*)d_in[1];
    const float* attn_w = (const float*)d_in[2];
    const float* attn_b = (const float*)d_in[3];
    const float* proj_w = (const float*)d_in[4];
    const float* proj_b = (const float*)d_in[5];
    const float* ln2_w  = (const float*)d_in[6];
    const float* li1_w  = (const float*)d_in[7];
    const float* li1_b  = (const float*)d_in[8];
    const float* li2_w  = (const float*)d_in[9];
    const float* li2_b  = (const float*)d_in[10];
    float* out = (float*)d_out;

    char* ws = (char*)d_ws;
    size_t off = 0;
    auto alloc = [&](size_t bytes) { void* p = ws + off; off += (bytes + 255) & ~(size_t)255; return p; };
    f16* W1t = (f16*)alloc((size_t)3072 * 1024 * 2);
    f16* W2t = (f16*)alloc((size_t)1024 * 1024 * 2);
    f16* W3t = (f16*)alloc((size_t)4096 * 1024 * 2);
    f16* W4t = (f16*)alloc((size_t)1024 * 4096 * 2);
    f16* h   = (f16*)alloc((size_t)4096 * 1024 * 2);
    f16* Qb  = (f16*)alloc((size_t)4096 * 1024 * 2);
    f16* Kb  = (f16*)alloc((size_t)4096 * 1024 * 2);
    f16* Vb  = (f16*)alloc((size_t)4096 * 1024 * 2);
    f16* Vt  = (f16*)alloc((size_t)4096 * 1024 * 2);
    f16* Ob  = (f16*)alloc((size_t)4096 * 1024 * 2);
    float* x1 = (float*)alloc((size_t)4096 * 1024 * 4);
    float* P  = (float*)alloc((size_t)2 * 4096 * 1024 * 4);  // split-K partials
    f16* Ab = Qb;  // 4096x4096 f16 aliases Qb..Vt (33.5 MB), dead after attention

    dim3 b328(32, 8);
    wconv_t<<<dim3(96, 32),  b328, 0, stream>>>(attn_w, W1t, 1024, 3072);
    wconv_t<<<dim3(32, 32),  b328, 0, stream>>>(proj_w, W2t, 1024, 1024);
    wconv_t<<<dim3(128, 32), b328, 0, stream>>>(li1_w,  W3t, 1024, 4096);
    wconv_t<<<dim3(32, 128), b328, 0, stream>>>(li2_w,  W4t, 4096, 1024);

    ln_kernel<<<4096, 256, 0, stream>>>(x, ln1_w, h);
    gemm256<0><<<dim3(16, 12), 512, 0, stream>>>(h, 1024, W1t, 1024, attn_b, nullptr,
                                                 nullptr, Qb, Kb, Vb, 3072, 1024);
    vtrans<<<dim3(32, 32), 256, 0, stream>>>(Vb, Vt);
    attn_kernel<<<256, 512, 0, stream>>>(Qb, Kb, Vt, Ob);
    gemm128<1><<<dim3(32, 8), 512, 0, stream>>>(Ob, 1024, W2t, 1024, proj_b, x,
                                                x1, nullptr, nullptr, nullptr, 1024, 1024);
    ln_kernel<<<4096, 256, 0, stream>>>(x1, ln2_w, h);
    gemm256<2><<<dim3(16, 16), 512, 0, stream>>>(h, 1024, W3t, 1024, li1_b, nullptr,
                                                 Ab, nullptr, nullptr, nullptr, 4096, 1024);
    // down-proj: split-K=2 (K=4096 -> 2x2048), 128^2 tile (512 blocks = 2/CU), fused reduce
    gemm128<3><<<dim3(32, 8, 2), 512, 0, stream>>>(Ab, 4096, W4t, 4096, nullptr, nullptr,
                                                   P, nullptr, nullptr, nullptr, 1024, 2048);
    kred<<<4096, 256, 0, stream>>>(P, P + (size_t)4096 * 1024, li2_b, x1, out);
}

// Round 21
// 246.259 us; speedup vs baseline: 1.0063x; 1.0014x over previous
//
#include <hip/hip_runtime.h>

typedef _Float16 f16;
typedef _Float16 f16x8 __attribute__((ext_vector_type(8)));
typedef _Float16 f16x4 __attribute__((ext_vector_type(4)));
typedef float    f32x4 __attribute__((ext_vector_type(4)));
typedef float    f32x16 __attribute__((ext_vector_type(16)));
typedef unsigned u32;
typedef unsigned u32x4 __attribute__((ext_vector_type(4)));

#define GAS __attribute__((address_space(1)))
#define LAS __attribute__((address_space(3)))

template <int N> struct IC { static constexpr int v = N; };

static __device__ __forceinline__ void gload_lds16(const void* g, void* l) {
    __builtin_amdgcn_global_load_lds((const GAS void*)g, (LAS void*)l, 16, 0, 0);
}

// ---------------- weight convert + transpose: fp32 [K,N] -> f16 [N,K] ----------------
__global__ void wconv_t(const float* __restrict__ w, f16* __restrict__ wt, int K, int N) {
    __shared__ f16 t[32][33];
    const int tx = threadIdx.x, ty = threadIdx.y;
    const int n0 = blockIdx.x * 32, k0 = blockIdx.y * 32;
#pragma unroll
    for (int i = 0; i < 4; i++)
        t[ty + i * 8][tx] = (f16)w[(size_t)(k0 + ty + i * 8) * N + n0 + tx];
    __syncthreads();
#pragma unroll
    for (int i = 0; i < 4; i++)
        wt[(size_t)(n0 + ty + i * 8) * K + k0 + tx] = t[tx][ty + i * 8];
}

// ---------------- LayerNorm fp32 -> f16 (D=1024, one row per block) ----------------
__global__ __launch_bounds__(256) void ln_kernel(const float* __restrict__ x,
                                                 const float* __restrict__ w,
                                                 f16* __restrict__ h) {
    const int row = blockIdx.x, tid = threadIdx.x;
    const float4 v = reinterpret_cast<const float4*>(x)[(size_t)row * 256 + tid];
    float s = v.x + v.y + v.z + v.w;
    float q = v.x * v.x + v.y * v.y + v.z * v.z + v.w * v.w;
#pragma unroll
    for (int m = 1; m < 64; m <<= 1) { s += __shfl_xor(s, m); q += __shfl_xor(q, m); }
    __shared__ float ss[4], qq[4];
    if ((tid & 63) == 0) { ss[tid >> 6] = s; qq[tid >> 6] = q; }
    __syncthreads();
    s = ss[0] + ss[1] + ss[2] + ss[3];
    q = qq[0] + qq[1] + qq[2] + qq[3];
    const float mu = s * (1.0f / 1024.0f);
    const float var = q * (1.0f / 1024.0f) - mu * mu;
    const float rs = rsqrtf(var + 1e-5f);
    const float4 wv = reinterpret_cast<const float4*>(w)[tid];
    f16x4 o;
    o[0] = (f16)((v.x - mu) * rs * wv.x);
    o[1] = (f16)((v.y - mu) * rs * wv.y);
    o[2] = (f16)((v.z - mu) * rs * wv.z);
    o[3] = (f16)((v.w - mu) * rs * wv.w);
    reinterpret_cast<f16x4*>(h)[(size_t)row * 256 + tid] = o;
}

// ---------------- V transpose: f16 [4096,1024] -> Vt f16 [32*64, 2048] ----------------
__global__ __launch_bounds__(256) void vtrans(const f16* __restrict__ V, f16* __restrict__ Vt) {
    __shared__ f16 tl[64][72];
    const int tid = threadIdx.x;
    const int t0 = blockIdx.x * 64, bh = blockIdx.y;
    const int b = bh >> 4, hh = bh & 15;
    const int rr = tid >> 3, cc = (tid & 7) * 8;
#pragma unroll
    for (int p = 0; p < 2; p++) {
        f16x8 v = *(const f16x8*)(V + (size_t)(b * 2048 + t0 + p * 32 + rr) * 1024 + hh * 64 + cc);
#pragma unroll
        for (int j = 0; j < 8; j++) tl[p * 32 + rr][cc + j] = v[j];
    }
    __syncthreads();
#pragma unroll
    for (int p = 0; p < 2; p++) {
        const int d = p * 32 + rr;
        f16x8 o;
#pragma unroll
        for (int j = 0; j < 8; j++) o[j] = tl[cc + j][d];
        *(f16x8*)(Vt + (size_t)(bh * 64 + d) * 2048 + t0 + cc) = o;
    }
}

// ============ GEMM epilogue (shared) ============
template <int EPI>
static __device__ __forceinline__ void gemm_epi(
    int gr, int gc, float v, int N, int gx,
    const float* bias, const float* res, void* outp,
    f16* oq, f16* ok, f16* ov, int bz, int BM) {
    if (EPI == 0) {
        if (gc < 1024)      oq[(size_t)gr * 1024 + gc]        = (f16)(v * 0.70710678118654752f);
        else if (gc < 2048) ok[(size_t)gr * 1024 + gc - 1024] = (f16)v;
        else                ov[(size_t)gr * 1024 + gc - 2048] = (f16)v;
    } else if (EPI == 1) {
        ((float*)outp)[(size_t)gr * N + gc] = v + res[(size_t)gr * N + gc];
    } else if (EPI == 2) {
        const float z = 0.7978845608028654f * (v + 0.044715f * v * v * v);
        const float t = 1.0f - 2.0f / (__builtin_amdgcn_exp2f(2.8853900817779268f * z) + 1.0f);
        ((f16*)outp)[(size_t)gr * N + gc] = (f16)(0.5f * v * (1.0f + t));
    } else {
        float* P = (float*)outp + (size_t)bz * ((size_t)gx * BM) * N;
        P[(size_t)gr * N + gc] = v;
    }
}

// ---------------- 256x256 8-phase GEMM, BK=64, 8 waves (2Mx4N) ----------------
// Coarse 8-phase (Round-15 best-measured: total 246.3us, 0 bank conflicts).
// Quarter-tiles {B0,B1,A0,A1} of 16KB (2 gload_lds/thread); per phase: stage 1 quarter,
// vmcnt(6), barrier, ds_read quadrant, 16 MFMA. Rows are 64 f16 (128B): full 8-slot XOR
// swizzle (slot ^= row&7) both sides -- attention-proven involution, spans all 32 banks.
template <int EPI>
__global__ __launch_bounds__(512, 2) void gemm256(
    const f16* __restrict__ A, int lda,
    const f16* __restrict__ Bt, int ldb,
    const float* __restrict__ bias,
    const float* __restrict__ res,
    void* __restrict__ outp,
    f16* __restrict__ oq, f16* __restrict__ ok, f16* __restrict__ ov,
    int N, int K) {
    __shared__ alignas(16) f16 pool[8 * 8192];   // 8 quarter-regions x 16KB = 128KB
    const int tid = threadIdx.x;
    const int lane = tid & 63, wv = tid >> 6;
    const int wr = wv >> 2, wc = wv & 3;          // 2M x 4N waves, wave-tile 128x64
    const int m0 = blockIdx.x * 256, n0 = blockIdx.y * 256;
    const int l15 = lane & 15, lg = lane >> 4;
    const int swz = l15 & 7;                      // read-side row swizzle (8-way)

    f32x4 acc[8][4] = {};
    f16x8 bf[4][2];

    // --- staging: thread t -> chunk row t>>3, LDS slot t&7, global col16 (t&7)^((t>>3)&7) ---
    const int gcol16 = (tid & 7) ^ ((tid >> 3) & 7);
    const f16* aSrc[2][2];
    const f16* bSrc[2][2];
#pragma unroll
    for (int c = 0; c < 2; c++) {
        const int lr = c * 64 + (tid >> 3);       // local row 0..127
#pragma unroll
        for (int h = 0; h < 2; h++) {
            const int ar = ((lr >> 5) << 6) + h * 32 + (lr & 31);   // A global row (half h)
            aSrc[c][h] = A + (size_t)(m0 + ar) * lda + gcol16 * 8;
            const int br = ((lr >> 6) << 7) + h * 64 + (lr & 63);   // B global row (half h)
            bSrc[c][h] = Bt + (size_t)(n0 + br) * ldb + gcol16 * 8;
        }
    }
    f16* ldst = pool + tid * 8;   // linear LDS dest: + region*8192 + c*4096 (f16 units)

    auto stageQ = [&](int par, int qid, int kt) {  // qid: 0=B0 1=B1 2=A0 3=A1
        f16* d = ldst + (par * 4 + qid) * 8192;
        if (qid >= 2) {
            gload_lds16(aSrc[0][qid - 2] + kt * 64, d);
            gload_lds16(aSrc[1][qid - 2] + kt * 64, d + 4096);
        } else {
            gload_lds16(bSrc[0][qid] + kt * 64, d);
            gload_lds16(bSrc[1][qid] + kt * 64, d + 4096);
        }
    };

    auto loadB = [&](int par) {
        // region wc&1, lr = (wc>>1)*64 + ni*16 + l15; slot (kk*4+lg)^swz
        const f16* bb = pool + par * 32768 + (wc & 1) * 8192 + (wc >> 1) * 4096 + l15 * 64;
#pragma unroll
        for (int ni = 0; ni < 4; ni++)
#pragma unroll
            for (int kk = 0; kk < 2; kk++)
                bf[ni][kk] = *(const f16x8*)(bb + ni * 1024 + (((kk * 4 + lg) ^ swz) * 8));
    };
    auto computeQ = [&](int par, auto qc) {
        constexpr int Q = decltype(qc)::v;
        // region 2+(Q&1), lr = wr*64 + (Q>>1)*32 + mi2*16 + l15
        const f16* ab = pool + par * 32768 + (2 + (Q & 1)) * 8192
                        + wr * 4096 + (Q >> 1) * 2048 + l15 * 64;
        f16x8 af[2][2];
#pragma unroll
        for (int mi2 = 0; mi2 < 2; mi2++)
#pragma unroll
            for (int kk = 0; kk < 2; kk++)
                af[mi2][kk] = *(const f16x8*)(ab + mi2 * 1024 + (((kk * 4 + lg) ^ swz) * 8));
        __builtin_amdgcn_s_setprio(1);
#pragma unroll
        for (int mi2 = 0; mi2 < 2; mi2++)
#pragma unroll
            for (int ni = 0; ni < 4; ni++)
#pragma unroll
                for (int kk = 0; kk < 2; kk++)
                    acc[Q * 2 + mi2][ni] = __builtin_amdgcn_mfma_f32_16x16x32_f16(
                        af[mi2][kk], bf[ni][kk], acc[Q * 2 + mi2][ni], 0, 0, 0);
        __builtin_amdgcn_s_setprio(0);
    };

#define VMW(n) asm volatile("s_waitcnt vmcnt(" #n ")" ::: "memory"); __builtin_amdgcn_s_barrier()

    const int nt = K >> 6;   // K-tiles of 64
    // prologue: all 4 quarters of tile 0 + B0 of tile 1
    stageQ(0, 0, 0); stageQ(0, 1, 0); stageQ(0, 2, 0); stageQ(0, 3, 0);
    stageQ(1, 0, 1);
    VMW(6);

    for (int kt = 0; kt < nt - 2; ++kt) {
        const int par = kt & 1, parn = par ^ 1;
        stageQ(parn, 1, kt + 1); VMW(6); loadB(par); computeQ(par, IC<0>{});
        stageQ(parn, 2, kt + 1); VMW(6); computeQ(par, IC<1>{});
        stageQ(parn, 3, kt + 1); VMW(6); computeQ(par, IC<2>{});
        stageQ(par, 0, kt + 2);  VMW(6); computeQ(par, IC<3>{});
    }
    {   // kt = nt-2: last full-stage tile (no B0 of tile nt)
        const int kt = nt - 2, par = kt & 1, parn = par ^ 1;
        stageQ(parn, 1, kt + 1); VMW(6); loadB(par); computeQ(par, IC<0>{});
        stageQ(parn, 2, kt + 1); VMW(6); computeQ(par, IC<1>{});
        stageQ(parn, 3, kt + 1); VMW(6); computeQ(par, IC<2>{});
        VMW(4); computeQ(par, IC<3>{});
    }
    {   // kt = nt-1: drain
        const int par = (nt - 1) & 1;
        VMW(2); loadB(par); computeQ(par, IC<0>{});
        VMW(0); computeQ(par, IC<1>{});
        computeQ(par, IC<2>{});
        computeQ(par, IC<3>{});
    }
#undef VMW

#pragma unroll
    for (int mi = 0; mi < 8; mi++)
#pragma unroll
        for (int ni = 0; ni < 4; ni++) {
            const int gc = n0 + wc * 64 + ni * 16 + l15;
            const float bb = (EPI == 3) ? 0.0f : bias[gc];
#pragma unroll
            for (int r = 0; r < 4; r++) {
                const int gr = m0 + wr * 128 + mi * 16 + lg * 4 + r;
                gemm_epi<EPI>(gr, gc, acc[mi][ni][r] + bb, N, gridDim.x,
                              bias, res, outp, oq, ok, ov, blockIdx.z, 256);
            }
        }
}

// ---------------- 128x128 GEMM, 8 waves (2Mx4N), wave-tile 64x32, vmcnt(2) (R10-proven) ----------------
template <int EPI>
__global__ __launch_bounds__(512) void gemm128(
    const f16* __restrict__ A, int lda,
    const f16* __restrict__ Bt, int ldb,
    const float* __restrict__ bias,
    const float* __restrict__ res,
    void* __restrict__ outp,
    f16* __restrict__ oq, f16* __restrict__ ok, f16* __restrict__ ov,
    int N, int K) {
    __shared__ alignas(16) f16 As[3][128 * 32];
    __shared__ alignas(16) f16 Bs[3][128 * 32];
    const int tid = threadIdx.x;
    const int lane = tid & 63, wv = tid >> 6;
    const int wr = wv >> 2, wc = wv & 3;
    const int m0 = blockIdx.x * 128, n0 = blockIdx.y * 128;
    const int l15 = lane & 15, lg = lane >> 4;

    f32x4 acc[4][2] = {};

    const int ar = tid >> 2;
    const int ac = (tid & 3) * 8;
    const size_t koff = (size_t)blockIdx.z * K;
    const f16* gA = A + (size_t)(m0 + ar) * lda + ac + koff;
    const f16* gB = Bt + (size_t)(n0 + ar) * ldb + ac + koff;
    char* lA0 = (char*)As + wv * 1024;
    char* lB0 = (char*)Bs + wv * 1024;

    auto stage = [&](int buf, int k0) {
        gload_lds16(gA + k0, lA0 + buf * 8192);
        gload_lds16(gB + k0, lB0 + buf * 8192);
    };
    auto compute = [&](int buf) {
        f16x8 af[4], bf[2];
#pragma unroll
        for (int i = 0; i < 4; i++)
            af[i] = *(const f16x8*)&As[buf][(wr * 64 + i * 16 + l15) * 32 + lg * 8];
#pragma unroll
        for (int n = 0; n < 2; n++)
            bf[n] = *(const f16x8*)&Bs[buf][(wc * 32 + n * 16 + l15) * 32 + lg * 8];
#pragma unroll
        for (int mi = 0; mi < 4; mi++)
#pragma unroll
            for (int ni = 0; ni < 2; ni++)
                acc[mi][ni] = __builtin_amdgcn_mfma_f32_16x16x32_f16(af[mi], bf[ni], acc[mi][ni], 0, 0, 0);
    };

    const int nk = K >> 5;
    stage(0, 0);
    if (nk > 1) {
        stage(1, 32);
        asm volatile("s_waitcnt vmcnt(2)" ::: "memory");
    } else {
        asm volatile("s_waitcnt vmcnt(0)" ::: "memory");
    }
    __builtin_amdgcn_s_barrier();

    for (int t = 0; t < nk; ++t) {
        const bool pref = (t + 2 < nk);
        if (pref) stage((t + 2) % 3, (t + 2) * 32);
        compute(t % 3);
        if (t + 1 < nk) {
            if (pref) asm volatile("s_waitcnt vmcnt(2)" ::: "memory");
            else      asm volatile("s_waitcnt vmcnt(0)" ::: "memory");
            __builtin_amdgcn_s_barrier();
        }
    }

#pragma unroll
    for (int mi = 0; mi < 4; mi++)
#pragma unroll
        for (int ni = 0; ni < 2; ni++) {
            const int gc = n0 + wc * 32 + ni * 16 + l15;
            const float bb = (EPI == 3) ? 0.0f : bias[gc];
#pragma unroll
            for (int r = 0; r < 4; r++) {
                const int gr = m0 + wr * 64 + mi * 16 + lg * 4 + r;
                gemm_epi<EPI>(gr, gc, acc[mi][ni][r] + bb, N, gridDim.x,
                              bias, res, outp, oq, ok, ov, blockIdx.z, 128);
            }
        }
}

// ---------------- split-K reduce: out = p0 + p1 + bias + res  (N = 1024 fp32) ----------------
__global__ __launch_bounds__(256) void kred(const float* __restrict__ p0,
                                            const float* __restrict__ p1,
                                            const float* __restrict__ bias,
                                            const float* __restrict__ res,
                                            float* __restrict__ out) {
    const size_t i = (size_t)blockIdx.x * 256 + threadIdx.x;
    const float4 a = ((const float4*)p0)[i];
    const float4 b = ((const float4*)p1)[i];
    const float4 r = ((const float4*)res)[i];
    const float4 w = ((const float4*)bias)[i & 255];
    float4 o;
    o.x = a.x + b.x + r.x + w.x;
    o.y = a.y + b.y + r.y + w.y;
    o.z = a.z + b.z + r.z + w.z;
    o.w = a.w + b.w + r.w + w.w;
    ((float4*)out)[i] = o;
}

// ---------------- causal flash attention: 8 waves, 8 interleaved qtiles, KVBLK=64 ----------------
__global__ __launch_bounds__(512) void attn_kernel(
    const f16* __restrict__ Q, const f16* __restrict__ Kb,
    const f16* __restrict__ Vt, f16* __restrict__ O) {
    __shared__ alignas(16) char pool[32768];
    const int tid = threadIdx.x, lane = tid & 63, w = tid >> 6;
    const int l31 = lane & 31, hi = lane >> 5;
    const int bx = blockIdx.x;
    const int qs = bx >> 5, bh = bx & 31;
    const int b = bh >> 4, hh = bh & 15;
    const int qtile = w * 8 + qs;
    const int q0 = qtile * 32;
    const int last = qtile >> 1;
    const int nk = ((56 + qs) >> 1) + 1;

    const f16* qrow = Q + (size_t)(b * 2048 + q0 + l31) * 1024 + hh * 64 + hi * 8;
    f16x8 qf[4];
#pragma unroll
    for (int s = 0; s < 4; s++) qf[s] = *(const f16x8*)(qrow + s * 16);

    f32x16 oacc[2] = {};
    float m = -3e38f, l = 0.0f;

    const int srow = tid >> 3, sslot = (tid & 7) ^ ((tid >> 3) & 7);
    const f16* kg = Kb + ((size_t)b * 2048 + srow) * 1024 + hh * 64 + sslot * 8;
    const f16* vg = Vt + ((size_t)bh * 64 + srow) * 2048 + sslot * 8;
    char* kld = pool + tid * 16;
    char* vld = pool + 8192 + tid * 16;

    auto stage = [&](int buf, int kt) {
        gload_lds16(kg + (size_t)kt * 65536, kld + buf * 16384);
        gload_lds16(vg + kt * 64, vld + buf * 16384);
    };

    const int rs = l31 & 7;

    auto tilestep = [&](int buf, bool diag) {
        const f16* Kbuf = (const f16*)(pool + buf * 16384);
        const f16* Vbuf = (const f16*)(pool + buf * 16384 + 8192);
        const bool doH1 = !diag || (qtile & 1);
        const int triH = qtile & 1;

        f16x8 k0[4], k1[4];
#pragma unroll
        for (int s = 0; s < 4; s++)
            k0[s] = *(const f16x8*)&Kbuf[l31 * 64 + (((s * 2 + hi) ^ rs) * 8)];
        if (doH1)
#pragma unroll
            for (int s = 0; s < 4; s++)
                k1[s] = *(const f16x8*)&Kbuf[(32 + l31) * 64 + (((s * 2 + hi) ^ rs) * 8)];

        f32x16 sacc0 = {}, sacc1 = {};
        __builtin_amdgcn_s_setprio(1);
#pragma unroll
        for (int s = 0; s < 4; s++)
            sacc0 = __builtin_amdgcn_mfma_f32_32x32x16_f16(k0[s], qf[s], sacc0, 0, 0, 0);
        if (doH1)
#pragma unroll
            for (int s = 0; s < 4; s++)
                sacc1 = __builtin_amdgcn_mfma_f32_32x32x16_f16(k1[s], qf[s], sacc1, 0, 0, 0);
        __builtin_amdgcn_s_setprio(0);

        if (diag) {
            if (triH == 0) {
#pragma unroll
                for (int r = 0; r < 16; r++) {
                    const int keyoff = (r & 3) + 8 * (r >> 2) + 4 * hi;
                    sacc0[r] = (keyoff > l31) ? -3e38f : sacc0[r];
                }
            } else {
#pragma unroll
                for (int r = 0; r < 16; r++) {
                    const int keyoff = (r & 3) + 8 * (r >> 2) + 4 * hi;
                    sacc1[r] = (keyoff > l31) ? -3e38f : sacc1[r];
                }
            }
        }
        float t8[8];
#pragma unroll
        for (int i = 0; i < 8; i++) t8[i] = fmaxf(sacc0[2 * i], sacc0[2 * i + 1]);
        if (doH1)
#pragma unroll
            for (int i = 0; i < 8; i++) t8[i] = fmaxf(t8[i], fmaxf(sacc1[2 * i], sacc1[2 * i + 1]));
#pragma unroll
        for (int i = 0; i < 4; i++) t8[i] = fmaxf(t8[i], t8[i + 4]);
        float tm = fmaxf(fmaxf(t8[0], t8[1]), fmaxf(t8[2], t8[3]));
        tm = fmaxf(tm, __shfl_xor(tm, 32));
        const bool up = tm > m + 8.0f;
        if (__any(up)) {
            const float mnew = up ? tm : m;
            const float alpha = __expf(m - mnew);
            m = mnew;
            l *= alpha;
#pragma unroll
            for (int r = 0; r < 16; r++) { oacc[0][r] *= alpha; oacc[1][r] *= alpha; }
        }
        const float mref = m * 1.44269504f;

        float psum = 0.0f;
        u32 wd[8];
        {
            float p[16];
#pragma unroll
            for (int r = 0; r < 16; r++)
                p[r] = __builtin_amdgcn_exp2f(sacc0[r] * 1.44269504f - mref);
            float s8[8];
#pragma unroll
            for (int i = 0; i < 8; i++) s8[i] = p[2 * i] + p[2 * i + 1];
#pragma unroll
            for (int i = 0; i < 4; i++) s8[i] = s8[i] + s8[i + 4];
            psum += (s8[0] + s8[1]) + (s8[2] + s8[3]);
#pragma unroll
            for (int i = 0; i < 8; i++)
                wd[i] = __builtin_bit_cast(u32, __builtin_amdgcn_cvt_pkrtz(p[2 * i], p[2 * i + 1]));
        }
        const u32 e0 = __shfl_xor(hi ? wd[0] : wd[2], 32);
        const u32 e1 = __shfl_xor(hi ? wd[1] : wd[3], 32);
        const u32 e2 = __shfl_xor(hi ? wd[4] : wd[6], 32);
        const u32 e3 = __shfl_xor(hi ? wd[5] : wd[7], 32);
        u32x4 c0, c1;
        c0[0] = hi ? e0 : wd[0]; c0[1] = hi ? e1 : wd[1];
        c0[2] = hi ? wd[2] : e0; c0[3] = hi ? wd[3] : e1;
        c1[0] = hi ? e2 : wd[4]; c1[1] = hi ? e3 : wd[5];
        c1[2] = hi ? wd[6] : e2; c1[3] = hi ? wd[7] : e3;
        const f16x8 pb00 = __builtin_bit_cast(f16x8, c0);
        const f16x8 pb01 = __builtin_bit_cast(f16x8, c1);

        f16x8 vfa, vfb;
        __builtin_amdgcn_s_setprio(1);
        vfa = *(const f16x8*)&Vbuf[l31 * 64 + ((hi ^ rs) * 8)];
        vfb = *(const f16x8*)&Vbuf[l31 * 64 + (((2 + hi) ^ rs) * 8)];
        oacc[0] = __builtin_amdgcn_mfma_f32_32x32x16_f16(vfa, pb00, oacc[0], 0, 0, 0);
        oacc[0] = __builtin_amdgcn_mfma_f32_32x32x16_f16(vfb, pb01, oacc[0], 0, 0, 0);
        vfa = *(const f16x8*)&Vbuf[(32 + l31) * 64 + ((hi ^ rs) * 8)];
        vfb = *(const f16x8*)&Vbuf[(32 + l31) * 64 + (((2 + hi) ^ rs) * 8)];
        oacc[1] = __builtin_amdgcn_mfma_f32_32x32x16_f16(vfa, pb00, oacc[1], 0, 0, 0);
        oacc[1] = __builtin_amdgcn_mfma_f32_32x32x16_f16(vfb, pb01, oacc[1], 0, 0, 0);
        __builtin_amdgcn_s_setprio(0);

        if (doH1) {
            float p[16];
#pragma unroll
            for (int r = 0; r < 16; r++)
                p[r] = __builtin_amdgcn_exp2f(sacc1[r] * 1.44269504f - mref);
            float s8[8];
#pragma unroll
            for (int i = 0; i < 8; i++) s8[i] = p[2 * i] + p[2 * i + 1];
#pragma unroll
            for (int i = 0; i < 4; i++) s8[i] = s8[i] + s8[i + 4];
            psum += (s8[0] + s8[1]) + (s8[2] + s8[3]);
#pragma unroll
            for (int i = 0; i < 8; i++)
                wd[i] = __builtin_bit_cast(u32, __builtin_amdgcn_cvt_pkrtz(p[2 * i], p[2 * i + 1]));
            const u32 f0 = __shfl_xor(hi ? wd[0] : wd[2], 32);
            const u32 f1 = __shfl_xor(hi ? wd[1] : wd[3], 32);
            const u32 f2 = __shfl_xor(hi ? wd[4] : wd[6], 32);
            const u32 f3 = __shfl_xor(hi ? wd[5] : wd[7], 32);
            u32x4 d0, d1;
            d0[0] = hi ? f0 : wd[0]; d0[1] = hi ? f1 : wd[1];
            d0[2] = hi ? wd[2] : f0; d0[3] = hi ? wd[3] : f1;
            d1[0] = hi ? f2 : wd[4]; d1[1] = hi ? f3 : wd[5];
            d1[2] = hi ? wd[6] : f2; d1[3] = hi ? wd[7] : f3;
            const f16x8 pb10 = __builtin_bit_cast(f16x8, d0);
            const f16x8 pb11 = __builtin_bit_cast(f16x8, d1);

            __builtin_amdgcn_s_setprio(1);
            vfa = *(const f16x8*)&Vbuf[l31 * 64 + (((4 + hi) ^ rs) * 8)];
            vfb = *(const f16x8*)&Vbuf[l31 * 64 + (((6 + hi) ^ rs) * 8)];
            oacc[0] = __builtin_amdgcn_mfma_f32_32x32x16_f16(vfa, pb10, oacc[0], 0, 0, 0);
            oacc[0] = __builtin_amdgcn_mfma_f32_32x32x16_f16(vfb, pb11, oacc[0], 0, 0, 0);
            vfa = *(const f16x8*)&Vbuf[(32 + l31) * 64 + (((4 + hi) ^ rs) * 8)];
            vfb = *(const f16x8*)&Vbuf[(32 + l31) * 64 + (((6 + hi) ^ rs) * 8)];
            oacc[1] = __builtin_amdgcn_mfma_f32_32x32x16_f16(vfa, pb10, oacc[1], 0, 0, 0);
            oacc[1] = __builtin_amdgcn_mfma_f32_32x32x16_f16(vfb, pb11, oacc[1], 0, 0, 0);
            __builtin_amdgcn_s_setprio(0);
        }
        psum += __shfl_xor(psum, 32);
        l += psum;
    };

    stage(0, 0);
    asm volatile("s_waitcnt vmcnt(0)" ::: "memory");
    __builtin_amdgcn_s_barrier();
    int buf = 0;
    for (int t = 0; t < nk; ++t) {
        if (t + 1 < nk) stage(buf ^ 1, t + 1);
        if (t <= last) tilestep(buf, t == last);
        asm volatile("s_waitcnt vmcnt(0)" ::: "memory");
        __builtin_amdgcn_s_barrier();
        buf ^= 1;
    }

    const float inv = 1.0f / l;
    f16* ot = (f16*)pool + (w & 3) * (32 * 72);
#pragma unroll
    for (int g = 0; g < 2; g++) {
        if ((w >> 2) == g) {
#pragma unroll
            for (int dt = 0; dt < 2; dt++)
#pragma unroll
                for (int r = 0; r < 16; r++) {
                    const int d = dt * 32 + (r & 3) + 8 * (r >> 2) + 4 * hi;
                    ot[l31 * 72 + d] = (f16)(oacc[dt][r] * inv);
                }
            asm volatile("s_waitcnt lgkmcnt(0)" ::: "memory");
#pragma unroll
            for (int i = 0; i < 4; i++) {
                const int row = i * 8 + (lane >> 3), col = (lane & 7) * 8;
                const f16x8 o8 = *(const f16x8*)&ot[row * 72 + col];
                *(f16x8*)(O + (size_t)(b * 2048 + q0 + row) * 1024 + hh * 64 + col) = o8;
            }
        }
        __syncthreads();
    }
}

extern "C" void kernel_launch(void* const* d_in, const int* in_sizes, int n_in,
                              void* d_out, int out_size, void* d_ws, size_t ws_size,
                              hipStream_t stream) {
    const float* x      = (const float*)d_in[0];
    const float* ln1_w  = (const float*)d_in[1];
    const float* attn_w = (const float*)d_in[2];
    const float* attn_b = (const float*)d_in[3];
    const float* proj_w = (const float*)d_in[4];
    const float* proj_b = (const float*)d_in[5];
    const float* ln2_w  = (const float*)d_in[6];
    const float* li1_w  = (const float*)d_in[7];
    const float* li1_b  = (const float*)d_in[8];
    const float* li2_w  = (const float*)d_in[9];
    const float* li2_b  = (const float*)d_in[10];
    float* out = (float*)d_out;

    char* ws = (char*)d_ws;
    size_t off = 0;
    auto alloc = [&](size_t bytes) { void* p = ws + off; off += (bytes + 255) & ~(size_t)255; return p; };
    f16* W1t = (f16*)alloc((size_t)3072 * 1024 * 2);
    f16* W2t = (f16*)alloc((size_t)1024 * 1024 * 2);
    f16* W3t = (f16*)alloc((size_t)4096 * 1024 * 2);
    f16* W4t = (f16*)alloc((size_t)1024 * 4096 * 2);
    f16* h   = (f16*)alloc((size_t)4096 * 1024 * 2);
    f16* Qb  = (f16*)alloc((size_t)4096 * 1024 * 2);
    f16* Kb  = (f16*)alloc((size_t)4096 * 1024 * 2);
    f16* Vb  = (f16*)alloc((size_t)4096 * 1024 * 2);
    f16* Vt  = (f16*)alloc((size_t)4096 * 1024 * 2);
    f16* Ob  = (f16*)alloc((size_t)4096 * 1024 * 2);
    float* x1 = (float*)alloc((size_t)4096 * 1024 * 4);
    float* P  = (float*)alloc((size_t)2 * 4096 * 1024 * 4);  // split-K partials
    f16* Ab = Qb;  // 4096x4096 f16 aliases Qb..Vt (33.5 MB), dead after attention

    dim3 b328(32, 8);
    wconv_t<<<dim3(96, 32),  b328, 0, stream>>>(attn_w, W1t, 1024, 3072);
    wconv_t<<<dim3(32, 32),  b328, 0, stream>>>(proj_w, W2t, 1024, 1024);
    wconv_t<<<dim3(128, 32), b328, 0, stream>>>(li1_w,  W3t, 1024, 4096);
    wconv_t<<<dim3(32, 128), b328, 0, stream>>>(li2_w,  W4t, 4096, 1024);

    ln_kernel<<<4096, 256, 0, stream>>>(x, ln1_w, h);
    gemm256<0><<<dim3(16, 12), 512, 0, stream>>>(h, 1024, W1t, 1024, attn_b, nullptr,
                                                 nullptr, Qb, Kb, Vb, 3072, 1024);
    vtrans<<<dim3(32, 32), 256, 0, stream>>>(Vb, Vt);
    attn_kernel<<<256, 512, 0, stream>>>(Qb, Kb, Vt, Ob);
    gemm128<1><<<dim3(32, 8), 512, 0, stream>>>(Ob, 1024, W2t, 1024, proj_b, x,
                                                x1, nullptr, nullptr, nullptr, 1024, 1024);
    ln_kernel<<<4096, 256, 0, stream>>>(x1, ln2_w, h);
    gemm256<2><<<dim3(16, 16), 512, 0, stream>>>(h, 1024, W3t, 1024, li1_b, nullptr,
                                                 Ab, nullptr, nullptr, nullptr, 4096, 1024);
    // down-proj: split-K=2 (K=4096 -> 2x2048), 128^2 tile (512 blocks = 2/CU), fused reduce
    gemm128<3><<<dim3(32, 8, 2), 512, 0, stream>>>(Ab, 4096, W4t, 4096, nullptr, nullptr,
                                                   P, nullptr, nullptr, nullptr, 1024, 2048);
    kred<<<4096, 256, 0, stream>>>(P, P + (size_t)4096 * 1024, li2_b, x1, out);
}